// Round 15
// baseline (392.232 us; speedup 1.0000x reference)
//
#include <hip/hip_runtime.h>
#include <math.h>

#define NN 50000
#define EE 800000
#define RR 8
#define SLOPE 0.2f
#define SEGS (NN * RR)            /* 400000 per-(node,relation) segments */
#define NTW ((NN + 63) / 64)      /* 782 mfma row-tiles (64 rows each) */
#define NBUK 98                   /* coarse buckets: dst>>9 (512 dst values each) */
#define SEGB 4096                 /* segments per bucket = 512 * RR */
#define EB4 ((EE + 4095) / 4096)  /* 196 fillA/hist blocks */
#define XB ((NN * 8 + 255) / 256) /* 1563 xh blocks */

typedef __attribute__((ext_vector_type(4))) float f32x4;
typedef _Float16 f16;
typedef __attribute__((ext_vector_type(4))) _Float16 h4;
typedef __attribute__((ext_vector_type(8))) _Float16 h8;

__device__ __forceinline__ void fmacc(float4& a, const float4& v, float p) {
    a.x = fmaf(v.x, p, a.x);
    a.y = fmaf(v.y, p, a.y);
    a.z = fmaf(v.z, p, a.z);
    a.w = fmaf(v.w, p, a.w);
}

__device__ __forceinline__ void red4(float4& a, int m) {
    a.x += __shfl_xor(a.x, m);
    a.y += __shfl_xor(a.y, m);
    a.z += __shfl_xor(a.z, m);
    a.w += __shfl_xor(a.w, m);
}

__device__ __forceinline__ float4 h4tof4(h4 t) {
    return make_float4((float)t[0], (float)t[1], (float)t[2], (float)t[3]);
}

__device__ __forceinline__ h4 hmax4(h4 a, h4 b) {
    h4 r;
    r[0] = a[0] > b[0] ? a[0] : b[0];
    r[1] = a[1] > b[1] ? a[1] : b[1];
    r[2] = a[2] > b[2] ? a[2] : b[2];
    r[3] = a[3] > b[3] ? a[3] : b[3];
    return r;
}

__device__ __forceinline__ h4 hsplat(f16 s) { return (h4){s, s, s, s}; }

// ============================ CSR build (bucket-local) + fused fp16 x copy ============================
__global__ __launch_bounds__(256) void k_histxh(const int* __restrict__ dst,
                                                int* __restrict__ buccnt,
                                                const float* __restrict__ X,
                                                f16* __restrict__ xh) {
    __shared__ int h[NBUK];
    int b = blockIdx.x;
    int tid = threadIdx.x;
    if (b < EB4) {  // histogram part
        for (int i = tid; i < NBUK; i += 256) h[i] = 0;
        __syncthreads();
        int e0 = b * 4096;
        int cnt = EE - e0;
        if (cnt > 4096) cnt = 4096;
        for (int i = tid; i < cnt; i += 256) atomicAdd(&h[dst[e0 + i] >> 9], 1);
        __syncthreads();
        for (int i = tid; i < NBUK; i += 256)
            if (h[i]) atomicAdd(&buccnt[i], h[i]);
    } else {  // xh part
        int i = (b - EB4) * 256 + tid;
        if (i >= NN * 8) return;
        float4 v0 = *(const float4*)(X + (size_t)i * 8);
        float4 v1 = *(const float4*)(X + (size_t)i * 8 + 4);
        h8 hv = {(f16)v0.x, (f16)v0.y, (f16)v0.z, (f16)v0.w,
                 (f16)v1.x, (f16)v1.y, (f16)v1.z, (f16)v1.w};
        *(h8*)(xh + (size_t)i * 8) = hv;
    }
}

__global__ void k_scan98(const int* __restrict__ buccnt, int* __restrict__ bucbase,
                         int* __restrict__ cbcur) {
    __shared__ int sh[128];
    int t = threadIdx.x;
    int v = (t < NBUK) ? buccnt[t] : 0;
    sh[t] = v;
    __syncthreads();
    for (int off = 1; off < 128; off <<= 1) {
        int u = (t >= off) ? sh[t - off] : 0;
        __syncthreads();
        sh[t] += u;
        __syncthreads();
    }
    int excl = sh[t] - v;
    if (t <= NBUK) bucbase[t] = excl;  // bucbase[NBUK] == EE
    if (t < NBUK) cbcur[t] = excl;
}

// ===== fill phase A: bin edges into recbuf in coarse-bucket-major order =====
__global__ __launch_bounds__(256) void k_fillA(const int* __restrict__ src,
                                               const int* __restrict__ dst,
                                               const int* __restrict__ et,
                                               int* __restrict__ cbcur,
                                               int* __restrict__ recbuf) {
    __shared__ int hist[NBUK], lcur[NBUK], gres[NBUK];
    int tid = threadIdx.x;
    int e0 = blockIdx.x * 4096;
    int cnt = EE - e0;
    if (cnt > 4096) cnt = 4096;
    for (int i = tid; i < NBUK; i += 256) { hist[i] = 0; lcur[i] = 0; }
    __syncthreads();
    int myb[16], myrec[16];
#pragma unroll
    for (int j = 0; j < 16; j++) {
        int i = tid + j * 256;
        if (i < cnt) {
            int e = e0 + i;
            int d = dst[e];
            int b = d >> 9;
            myb[j] = b;
            myrec[j] = ((d & 511) << 19) | (src[e] << 3) | et[e];
            atomicAdd(&hist[b], 1);
        } else {
            myb[j] = -1;
            myrec[j] = 0;
        }
    }
    __syncthreads();
    if (tid < NBUK) gres[tid] = atomicAdd(&cbcur[tid], hist[tid]);
    __syncthreads();
#pragma unroll
    for (int j = 0; j < 16; j++) {
        if (myb[j] >= 0) {
            int p = atomicAdd(&lcur[myb[j]], 1);
            recbuf[gres[myb[j]] + p] = myrec[j];
        }
    }
}

// ===== fill phase B2: one block per bucket; counts+scan+rp-write+scatter in LDS =====
__global__ __launch_bounds__(256) void k_fillB2(const int* __restrict__ bucbase,
                                                const int* __restrict__ recbuf,
                                                int* __restrict__ rp,
                                                int* __restrict__ srcs2) {
    __shared__ int cnt[SEGB];
    __shared__ int psc[256];
    int b = blockIdx.x;
    int segbase = b * SEGB;
    int nseg = SEGS - segbase;
    if (nseg > SEGB) nseg = SEGB;
    int base = bucbase[b];
    int cntE = bucbase[b + 1] - base;
    int tid = threadIdx.x;
    for (int s = tid; s < SEGB; s += 256) cnt[s] = 0;
    __syncthreads();
    for (int i = tid; i < cntE; i += 256) {
        int rec = recbuf[base + i];
        int segl = ((rec >> 19) << 3) | (rec & 7);
        atomicAdd(&cnt[segl], 1);
    }
    __syncthreads();
    int loc[16];
    int sbase = tid * 16;
    int run = 0;
#pragma unroll
    for (int j = 0; j < 16; j++) { loc[j] = cnt[sbase + j]; run += loc[j]; }
    psc[tid] = run;
    __syncthreads();
    for (int off = 1; off < 256; off <<= 1) {
        int u = (tid >= off) ? psc[tid - off] : 0;
        __syncthreads();
        psc[tid] += u;
        __syncthreads();
    }
    int excl = psc[tid] - run;
#pragma unroll
    for (int j = 0; j < 16; j++) {
        int s = sbase + j;
        int v = loc[j];
        cnt[s] = excl;
        if (s < nseg) rp[segbase + s] = base + excl;
        excl += v;
    }
    __syncthreads();
    for (int i = tid; i < cntE; i += 256) {
        int rec = recbuf[base + i];
        int segl = ((rec >> 19) << 3) | (rec & 7);
        int p = atomicAdd(&cnt[segl], 1);
        srcs2[base + p] = rec & 0x7FFFF;
    }
    if (b == NBUK - 1 && tid == 0) rp[SEGS] = EE;
}

// ==== prep (merged): padded weights, logit projections, stacked Wb1, Wcat2e compose ====
__global__ void k_prep(const float* __restrict__ wg1, const float* __restrict__ wg2,
                       const float* __restrict__ root1, const float* __restrict__ root2,
                       const float* __restrict__ basis1, const float* __restrict__ basis2,
                       const float* __restrict__ comp2,
                       const float* __restrict__ asrc1, const float* __restrict__ adst1,
                       const float* __restrict__ asrc2, const float* __restrict__ adst2,
                       float* __restrict__ Wcat2e, float* __restrict__ wg1r,
                       float* __restrict__ Wstk, float* __restrict__ U1p,
                       float* __restrict__ U2p, float* __restrict__ Wb1) {
    int idx = blockIdx.x * 256 + threadIdx.x;
    if (idx < 16384) {  // wg1r[h][k][c] (c<32 valid)
        int h = idx >> 12, kc = idx & 4095;
        int k = kc >> 6, c = kc & 63;
        wg1r[idx] = (c < 32) ? wg1[k * 128 + h * 32 + c] : 0.f;
    } else if (idx < 24576) {  // Wstk[h*32+k][c] = wg2[k][h*16+c] (c<16 valid)
        int j = idx - 16384;
        int row = j >> 6, c = j & 63;
        int h = row >> 5, k = row & 31;
        Wstk[j] = (c < 16) ? wg2[k * 64 + h * 16 + c] : 0.f;
    } else if (idx < 32768) {  // Wcat2e root block: [128][col 0-63] = root2 zero-padded
        int j = idx - 24576;
        int k = j >> 6, c = j & 63;
        Wcat2e[k * 320 + c] = (c < 32) ? root2[k * 32 + c] : 0.f;
    } else if (idx < 36864) {  // U1p[k][j]
        int j0 = idx - 32768;
        int k = j0 >> 6, j = j0 & 63;
        float s = 0.f;
        if (j < 8) {
            int h = j & 3;
            const float* a = (j < 4) ? asrc1 : adst1;
            for (int c = 0; c < 32; c++) s += wg1[k * 128 + h * 32 + c] * a[h * 32 + c];
        }
        U1p[j0] = s;
    } else if (idx < 38912) {  // U2p[k][j]
        int j0 = idx - 36864;
        int k = j0 >> 6, j = j0 & 63;
        float s = 0.f;
        if (j < 8) {
            int h = j & 3;
            const float* a = (j < 4) ? asrc2 : adst2;
            for (int c = 0; c < 16; c++) s += wg2[k * 64 + h * 16 + c] * a[h * 16 + c];
        }
        U2p[j0] = s;
    } else if (idx < 55296) {  // Wb1 rows 0-255 = basis1 flat copy
        Wb1[idx - 38912] = basis1[idx - 38912];
    } else if (idx < 59392) {  // Wb1 rows 256-319 = root1
        Wb1[idx - 38912] = root1[idx - 55296];
    } else if (idx < 92160) {  // Wcat2e basis-composed block: [128][col 64-319]
        int j = idx - 59392;
        int i = j >> 8, rc = j & 255;
        int r = rc >> 5, o = rc & 31;
        float acc = 0.f;
#pragma unroll
        for (int b = 0; b < 4; b++) acc += comp2[r * 4 + b] * basis2[b * 4096 + i * 32 + o];
        Wcat2e[i * 320 + 64 + rc] = acc;
    }
}

// ==== pack weights into fp16 hi/lo MFMA fragment order (A is fp16 -> native f16 MFMA) ====
__global__ void k_pack(const float* __restrict__ Wb1, const float* __restrict__ wg1r,
                       const float* __restrict__ Wcat, short* __restrict__ pWb1,
                       short* __restrict__ pwg1r, short* __restrict__ pWcat) {
    int u = blockIdx.x * 256 + threadIdx.x;
    int lane = u & 63, pair = u >> 6;
    if (pair >= 136) return;
    int m = lane & 15, g = lane >> 4;
    const float* src;
    int ldB, col, k0;
    short* dst;
    if (pair < 40) {
        int ct = pair / 10, kc = pair % 10;
        src = Wb1; ldB = 64; col = ct * 16 + m; k0 = kc * 32 + g * 8;
        dst = pWb1 + pair * 1024 + lane * 8;
    } else if (pair < 56) {
        int q = pair - 40;
        int h = q >> 2, lp = q & 3, ct = lp >> 1, kc = lp & 1;
        src = wg1r + h * 4096; ldB = 64; col = ct * 16 + m; k0 = kc * 32 + g * 8;
        dst = pwg1r + q * 1024 + lane * 8;
    } else {
        int q = pair - 56;
        int p = q >> 4, lp = q & 15, ct = lp >> 2, kc = lp & 3;
        src = Wcat; ldB = 320; col = p * 64 + ct * 16 + m; k0 = kc * 32 + g * 8;
        dst = pWcat + q * 1024 + lane * 8;
    }
    h8 H, L;
#pragma unroll
    for (int r = 0; r < 8; r++) {
        float e = src[(size_t)(k0 + r) * ldB + col];
        f16 hi = (f16)e;
        H[r] = hi;
        L[r] = (f16)(e - (float)hi);
    }
    *(h8*)dst = H;
    *(h8*)(dst + 512) = L;
}

// ============ MFMA GEMM (fp16 A, fp16 hi/lo B, 2-term): 4 waves x 16 rows, NCOL cols ============
template <int KTOT, int NCOL, int ACT = 0, int OUTH = 0>
__global__ __launch_bounds__(256) void k_mfma(const f16* __restrict__ X, int ldX, int xmb,
                                              const short* __restrict__ Bpk, int bmb,
                                              float* __restrict__ Y, int ldY, size_t ymb,
                                              const float* __restrict__ bias, int biasmb) {
    constexpr int NKC = KTOT / 32;
    constexpr int NCT = NCOL / 16;
    const int tid = threadIdx.x;
    const int wid = tid >> 6, lane = tid & 63;
    const int m = lane & 15, g = lane >> 4;
    const int mb = blockIdx.y;
    const int rowbase = blockIdx.x * 64 + wid * 16;
    if (rowbase >= NN) return;  // NN % 16 == 0: per-wave all-or-nothing
    const f16* Xm = X + (size_t)mb * xmb + (size_t)(rowbase + m) * ldX;
    const short* Bm = Bpk + (size_t)mb * bmb;

    f32x4 acc[NCT];
#pragma unroll
    for (int c = 0; c < NCT; c++) acc[c] = (f32x4){0.f, 0.f, 0.f, 0.f};

#pragma unroll
    for (int kc = 0; kc < NKC; kc++) {
        h8 av = *(const h8*)(Xm + kc * 32 + g * 8);
#pragma unroll
        for (int ct = 0; ct < NCT; ct++) {
            const short* bp = Bm + (size_t)(ct * NKC + kc) * 1024 + lane * 8;
            h8 bh = *(const h8*)bp;
            h8 bl = *(const h8*)(bp + 512);
            acc[ct] = __builtin_amdgcn_mfma_f32_16x16x32_f16(av, bh, acc[ct], 0, 0, 0);
            acc[ct] = __builtin_amdgcn_mfma_f32_16x16x32_f16(av, bl, acc[ct], 0, 0, 0);
        }
    }

#pragma unroll
    for (int ct = 0; ct < NCT; ct++) {
        int col = ct * 16 + m;
        float bv = bias ? bias[mb * biasmb + col] : 0.f;
#pragma unroll
        for (int i = 0; i < 4; i++) {
            float o = acc[ct][i] + bv;
            if (ACT == 2) o = fmaxf(o, 0.f);
            if (OUTH) {
                f16* Yh = (f16*)Y;
                Yh[(size_t)mb * ymb + (size_t)(rowbase + g * 4 + i) * ldY + col] = (f16)o;
            } else {
                Y[(size_t)mb * ymb + (size_t)(rowbase + g * 4 + i) * ldY + col] = o;
            }
        }
    }
}

// ===== L3 transform: 18 live col-tiles split 6-per-blockIdx.y (fp16 2-term MFMA) =====
__global__ __launch_bounds__(256) void k_mfmaL3(const f16* __restrict__ Xh,
                                                const short* __restrict__ Bpk,
                                                float* __restrict__ x3,
                                                f16* __restrict__ ybuf3h) {
    const int tid = threadIdx.x;
    const int wid = tid >> 6, lane = tid & 63;
    const int m = lane & 15, g = lane >> 4;
    const int y = blockIdx.y;
    const int rowbase = blockIdx.x * 64 + wid * 16;
    if (rowbase >= NN) return;
    const f16* Xm = Xh + (size_t)(rowbase + m) * 128;

    f32x4 acc[6];
#pragma unroll
    for (int j = 0; j < 6; j++) acc[j] = (f32x4){0.f, 0.f, 0.f, 0.f};

#pragma unroll
    for (int kc = 0; kc < 4; kc++) {
        h8 av = *(const h8*)(Xm + kc * 32 + g * 8);
#pragma unroll
        for (int j = 0; j < 6; j++) {
            int bct = (y == 0) ? ((j < 2) ? j : j + 2) : (8 + (y - 1) * 6 + j);
            const short* bp = Bpk + (size_t)(bct * 4 + kc) * 1024 + lane * 8;
            h8 bh = *(const h8*)bp;
            h8 bl = *(const h8*)(bp + 512);
            acc[j] = __builtin_amdgcn_mfma_f32_16x16x32_f16(av, bh, acc[j], 0, 0, 0);
            acc[j] = __builtin_amdgcn_mfma_f32_16x16x32_f16(av, bl, acc[j], 0, 0, 0);
        }
    }
#pragma unroll
    for (int j = 0; j < 6; j++) {
        int bct = (y == 0) ? ((j < 2) ? j : j + 2) : (8 + (y - 1) * 6 + j);
        if (bct < 2) {  // root cols 0-31 -> x3 fp32 compact [n][32]
            int col = bct * 16 + m;
#pragma unroll
            for (int r = 0; r < 4; r++) {
                int n = rowbase + g * 4 + r;
                x3[(size_t)n * 32 + col] = acc[j][r];
            }
        } else {  // rel col gcol = bct*16+m-64 -> panel p, col cc (fp16)
            int gcol = bct * 16 + m - 64;
            int p = gcol >> 6, cc = gcol & 63;
            f16* Yp = ybuf3h + (size_t)p * NN * 64;
#pragma unroll
            for (int r = 0; r < 4; r++) {
                int n = rowbase + g * 4 + r;
                Yp[(size_t)n * 64 + cc] = (f16)acc[j][r];
            }
        }
    }
}

// ===== L1 basis-space gather: packed-fp16 accumulation; U[n][b][64]; U[n][4][64]=x[n] =====
__global__ __launch_bounds__(256) void k_gagg1(const int* __restrict__ rp,
                                               const int* __restrict__ srcs2,
                                               const float* __restrict__ comp,
                                               const f16* __restrict__ Xh,
                                               f16* __restrict__ Uh) {
    __shared__ h4 sh_w[4][8];
    int wid = threadIdx.x >> 6, lane = threadIdx.x & 63;
    int n = blockIdx.x * 4 + wid;
    int rpv = (lane <= 8) ? rp[n * RR + lane] : 0;
    int nxt = __shfl(rpv, (lane + 1) & 63);
    if (lane < 8) {
        float inv = 1.f / (float)((nxt - rpv) > 0 ? (nxt - rpv) : 1);
        float4 c = *(const float4*)(comp + lane * 4);
        sh_w[wid][lane] = (h4){(f16)(c.x * inv), (f16)(c.y * inv),
                               (f16)(c.z * inv), (f16)(c.w * inv)};
    }
    int q = lane & 15;
    int beg = rp[n * RR], end = rp[n * RR + RR];
    h4 hz = {(f16)0.f, (f16)0.f, (f16)0.f, (f16)0.f};
    h4 a0 = hz, a1 = hz, a2 = hz, a3 = hz;
    int k = beg + (lane >> 4);
    for (; k + 4 < end; k += 8) {
        int key0 = srcs2[k], key1 = srcs2[k + 4];
        h4 w0 = sh_w[wid][key0 & 7], w1 = sh_w[wid][key1 & 7];
        h4 v0 = *(const h4*)(Xh + (size_t)(key0 >> 3) * 64 + q * 4);
        h4 v1 = *(const h4*)(Xh + (size_t)(key1 >> 3) * 64 + q * 4);
        a0 += hsplat(w0[0]) * v0;
        a1 += hsplat(w0[1]) * v0;
        a2 += hsplat(w0[2]) * v0;
        a3 += hsplat(w0[3]) * v0;
        a0 += hsplat(w1[0]) * v1;
        a1 += hsplat(w1[1]) * v1;
        a2 += hsplat(w1[2]) * v1;
        a3 += hsplat(w1[3]) * v1;
    }
    if (k < end) {
        int key0 = srcs2[k];
        h4 w0 = sh_w[wid][key0 & 7];
        h4 v0 = *(const h4*)(Xh + (size_t)(key0 >> 3) * 64 + q * 4);
        a0 += hsplat(w0[0]) * v0;
        a1 += hsplat(w0[1]) * v0;
        a2 += hsplat(w0[2]) * v0;
        a3 += hsplat(w0[3]) * v0;
    }
    float4 A0 = h4tof4(a0), A1 = h4tof4(a1), A2 = h4tof4(a2), A3 = h4tof4(a3);
    red4(A0, 16); red4(A0, 32);
    red4(A1, 16); red4(A1, 32);
    red4(A2, 16); red4(A2, 32);
    red4(A3, 16); red4(A3, 32);
    if (lane < 16) {
        f16* un = Uh + (size_t)n * 320;
        h4 o0 = {(f16)A0.x, (f16)A0.y, (f16)A0.z, (f16)A0.w};
        h4 o1 = {(f16)A1.x, (f16)A1.y, (f16)A1.z, (f16)A1.w};
        h4 o2 = {(f16)A2.x, (f16)A2.y, (f16)A2.z, (f16)A2.w};
        h4 o3 = {(f16)A3.x, (f16)A3.y, (f16)A3.z, (f16)A3.w};
        *(h4*)(un + 0 * 64 + q * 4) = o0;
        *(h4*)(un + 1 * 64 + q * 4) = o1;
        *(h4*)(un + 2 * 64 + q * 4) = o2;
        *(h4*)(un + 3 * 64 + q * 4) = o3;
        *(h4*)(un + 256 + q * 4) = *(const h4*)(Xh + (size_t)n * 64 + q * 4);
    }
}

// ===== skinny matvec on fp16 x1h + fp16 exp-logit emit =====
__global__ __launch_bounds__(256) void k_alds1(const f16* __restrict__ X1h,
                                               const float* __restrict__ U1p,
                                               f16* __restrict__ aldsEh) {
    __shared__ float sUT[8 * 68];
    int tid = threadIdx.x;
    for (int i = tid; i < 512; i += 256) {
        int j = i >> 6, c = i & 63;
        sUT[j * 68 + c] = U1p[c * 64 + j];
    }
    __syncthreads();
    int lane = tid & 63, wid = tid >> 6;
    int n = blockIdx.x * 32 + wid * 8 + (lane >> 3);
    int q = lane & 7;
    float x[8];
    if (n < NN) {
        h8 hv = *(const h8*)(X1h + (size_t)n * 64 + q * 8);
#pragma unroll
        for (int c = 0; c < 8; c++) x[c] = (float)hv[c];
    } else {
#pragma unroll
        for (int c = 0; c < 8; c++) x[c] = 0.f;
    }
    float al[8];
#pragma unroll
    for (int j = 0; j < 8; j++) {
        const float* u = &sUT[j * 68 + q * 8];
        float s = 0.f;
#pragma unroll
        for (int c = 0; c < 8; c++) s += x[c] * u[c];
        al[j] = s;
    }
#pragma unroll
    for (int m = 1; m < 8; m <<= 1)
#pragma unroll
        for (int j = 0; j < 8; j++) al[j] += __shfl_xor(al[j], m);
    if (n < NN) {
        float av = al[q];
        int pos = (q < 4) ? q : q + 4;  // Es 0-3, Es2 4-7, Ed 8-11, Ed2 12-15
        aldsEh[(size_t)n * 16 + pos] = (f16)__expf(av);
        aldsEh[(size_t)n * 16 + pos + 4] = (f16)__expf(SLOPE * av);
    }
}

// ===== aggregate 2 + fused fp16 exp-logit emit (x3prev compact [n][32] fp32) =====
__global__ __launch_bounds__(256) void k_agg2(const int* __restrict__ rp,
                                              const int* __restrict__ srcs2,
                                              const f16* __restrict__ y,
                                              const float* __restrict__ bias,
                                              const float* __restrict__ U2p,
                                              const float* __restrict__ x3prev,
                                              f16* __restrict__ x3h,
                                              f16* __restrict__ aldsEh) {
    __shared__ float sh_inv[4][8];
    int wid = threadIdx.x >> 6, lane = threadIdx.x & 63;
    int n = blockIdx.x * 4 + wid;
    int rpv = (lane <= 8) ? rp[n * RR + lane] : 0;
    int nxt = __shfl(rpv, (lane + 1) & 63);
    if (lane < 8) sh_inv[wid][lane] = 1.f / (float)((nxt - rpv) > 0 ? (nxt - rpv) : 1);
    int q = lane & 7;
    int beg = rp[n * RR], end = rp[n * RR + RR];
    float4 acc = make_float4(0.f, 0.f, 0.f, 0.f);
    int k = beg + (lane >> 3);
    for (; k + 8 < end; k += 16) {
        int key0 = srcs2[k], key1 = srcs2[k + 8];
        int s0 = key0 >> 3, s1 = key1 >> 3;
        int g0 = key0 & 7, g1 = key1 & 7;
        float e0 = sh_inv[wid][g0], e1 = sh_inv[wid][g1];
        float4 v0 = h4tof4(*(const h4*)(y + ((size_t)(g0 >> 1) * NN + s0) * 64 + (g0 & 1) * 32 + q * 4));
        float4 v1 = h4tof4(*(const h4*)(y + ((size_t)(g1 >> 1) * NN + s1) * 64 + (g1 & 1) * 32 + q * 4));
        fmacc(acc, v0, e0);
        fmacc(acc, v1, e1);
    }
    if (k < end) {
        int key0 = srcs2[k];
        int s0 = key0 >> 3;
        int g0 = key0 & 7;
        float4 v0 = h4tof4(*(const h4*)(y + ((size_t)(g0 >> 1) * NN + s0) * 64 + (g0 & 1) * 32 + q * 4));
        fmacc(acc, v0, sh_inv[wid][g0]);
    }
    red4(acc, 8);
    red4(acc, 16);
    red4(acc, 32);
    if (lane < 8) {
        float4 prev = *(const float4*)(x3prev + (size_t)n * 32 + q * 4);
        float4 b = *(const float4*)(bias + q * 4);
        float4 v;
        v.x = fmaxf(prev.x + acc.x + b.x, 0.f);
        v.y = fmaxf(prev.y + acc.y + b.y, 0.f);
        v.z = fmaxf(prev.z + acc.z + b.z, 0.f);
        v.w = fmaxf(prev.w + acc.w + b.w, 0.f);
        h4 hv = {(f16)v.x, (f16)v.y, (f16)v.z, (f16)v.w};
        *(h4*)(x3h + (size_t)n * 32 + q * 4) = hv;
        float al[8];
#pragma unroll
        for (int j = 0; j < 8; j++) {
            al[j] = fmaf(v.x, U2p[(q * 4 + 0) * 64 + j],
                    fmaf(v.y, U2p[(q * 4 + 1) * 64 + j],
                    fmaf(v.z, U2p[(q * 4 + 2) * 64 + j],
                         v.w * U2p[(q * 4 + 3) * 64 + j])));
        }
#pragma unroll
        for (int m = 1; m < 8; m <<= 1) {
#pragma unroll
            for (int j = 0; j < 8; j++) al[j] += __shfl_xor(al[j], m);
        }
        float av = al[q];
        int pos = (q < 4) ? q : q + 4;
        aldsEh[(size_t)n * 16 + pos] = (f16)__expf(av);
        aldsEh[(size_t)n * 16 + pos + 4] = (f16)__expf(SLOPE * av);
    }
}

// ===== fused GAT aggregation (layer 2, F=64): packed-fp16 logits AND accumulation =====
__global__ __launch_bounds__(256) void k_gatx64(const int* __restrict__ rp,
                                                const int* __restrict__ srcs2,
                                                const f16* __restrict__ aldsEh,
                                                const f16* __restrict__ X,
                                                f16* __restrict__ msg) {
    constexpr int F = 64, LDX = 64;
    constexpr int G = F / 4;    // 16 lanes per edge-group
    constexpr int NG = 64 / G;  // 4 groups per wave
    int wid = threadIdx.x >> 6, lane = threadIdx.x & 63;
    int n = blockIdx.x * 4 + wid;
    if (n >= NN) return;
    int g = lane / G, q = lane % G;
    h4 EdH = *(const h4*)(aldsEh + (size_t)n * 16 + 8);
    h4 Ed2H = *(const h4*)(aldsEh + (size_t)n * 16 + 12);
    h4 hz = {(f16)0.f, (f16)0.f, (f16)0.f, (f16)0.f};
    h4 acc0 = hz, acc1 = hz, acc2 = hz, acc3 = hz, zH = hz;
    if (g == 0) {  // self loop
        h4 es = *(const h4*)(aldsEh + (size_t)n * 16);
        h4 es2 = *(const h4*)(aldsEh + (size_t)n * 16 + 4);
        h4 xv = *(const h4*)(X + (size_t)n * LDX + q * 4);
        h4 pH = hmax4(es * EdH, es2 * Ed2H);
        zH += pH;
        acc0 += hsplat(pH[0]) * xv;
        acc1 += hsplat(pH[1]) * xv;
        acc2 += hsplat(pH[2]) * xv;
        acc3 += hsplat(pH[3]) * xv;
    }
    int beg = rp[n * RR], end = rp[n * RR + RR];
    int k = beg + g;
    for (; k + NG < end; k += 2 * NG) {
        int s0 = srcs2[k] >> 3, s1 = srcs2[k + NG] >> 3;
        h8 e0 = *(const h8*)(aldsEh + (size_t)s0 * 16);
        h8 e1 = *(const h8*)(aldsEh + (size_t)s1 * 16);
        h4 x0 = *(const h4*)(X + (size_t)s0 * LDX + q * 4);
        h4 x1v = *(const h4*)(X + (size_t)s1 * LDX + q * 4);
        h4 e0lo = {e0[0], e0[1], e0[2], e0[3]};
        h4 e0hi = {e0[4], e0[5], e0[6], e0[7]};
        h4 e1lo = {e1[0], e1[1], e1[2], e1[3]};
        h4 e1hi = {e1[4], e1[5], e1[6], e1[7]};
        h4 p0H = hmax4(e0lo * EdH, e0hi * Ed2H);
        h4 p1H = hmax4(e1lo * EdH, e1hi * Ed2H);
        zH += p0H + p1H;
        acc0 += hsplat(p0H[0]) * x0;
        acc1 += hsplat(p0H[1]) * x0;
        acc2 += hsplat(p0H[2]) * x0;
        acc3 += hsplat(p0H[3]) * x0;
        acc0 += hsplat(p1H[0]) * x1v;
        acc1 += hsplat(p1H[1]) * x1v;
        acc2 += hsplat(p1H[2]) * x1v;
        acc3 += hsplat(p1H[3]) * x1v;
    }
    if (k < end) {
        int s0 = srcs2[k] >> 3;
        h8 e0 = *(const h8*)(aldsEh + (size_t)s0 * 16);
        h4 x0 = *(const h4*)(X + (size_t)s0 * LDX + q * 4);
        h4 e0lo = {e0[0], e0[1], e0[2], e0[3]};
        h4 e0hi = {e0[4], e0[5], e0[6], e0[7]};
        h4 p0H = hmax4(e0lo * EdH, e0hi * Ed2H);
        zH += p0H;
        acc0 += hsplat(p0H[0]) * x0;
        acc1 += hsplat(p0H[1]) * x0;
        acc2 += hsplat(p0H[2]) * x0;
        acc3 += hsplat(p0H[3]) * x0;
    }
    float4 A0 = h4tof4(acc0), A1 = h4tof4(acc1), A2 = h4tof4(acc2), A3 = h4tof4(acc3);
    float4 z = h4tof4(zH);
#pragma unroll
    for (int m = G; m < 64; m <<= 1) {
        red4(A0, m);
        red4(A1, m);
        red4(A2, m);
        red4(A3, m);
        red4(z, m);
    }
    if (g == 0) {
        float4 iz = make_float4(1.f / z.x, 1.f / z.y, 1.f / z.z, 1.f / z.w);
        f16* mp = msg + (size_t)n * 4 * F + q * 4;
        h4 o0 = {(f16)(A0.x * iz.x), (f16)(A0.y * iz.x), (f16)(A0.z * iz.x), (f16)(A0.w * iz.x)};
        h4 o1 = {(f16)(A1.x * iz.y), (f16)(A1.y * iz.y), (f16)(A1.z * iz.y), (f16)(A1.w * iz.y)};
        h4 o2 = {(f16)(A2.x * iz.z), (f16)(A2.y * iz.z), (f16)(A2.z * iz.z), (f16)(A2.w * iz.z)};
        h4 o3 = {(f16)(A3.x * iz.w), (f16)(A3.y * iz.w), (f16)(A3.z * iz.w), (f16)(A3.w * iz.w)};
        *(h4*)(mp + 0 * F) = o0;
        *(h4*)(mp + 1 * F) = o1;
        *(h4*)(mp + 2 * F) = o2;
        *(h4*)(mp + 3 * F) = o3;
    }
}

// ===== fused GAT layer 4 (F=32) + final matvec/tanh via LDS redistribution =====
// Phase 1: per-wave gatx body (1 node/wave, 8 edge-groups x 8 lanes); g==0 lanes deposit
// normalized msg[n][128] into LDS (fp32). Phase 2: all 256 threads compute the 4 nodes'
// out[16] = tanh(relu(0.25 * msg . Wstk + bg2)) -- thread = (node, col, k-quarter).
__global__ __launch_bounds__(256) void k_gatx32f(const int* __restrict__ rp,
                                                 const int* __restrict__ srcs2,
                                                 const f16* __restrict__ aldsEh,
                                                 const f16* __restrict__ X,
                                                 const float* __restrict__ Wstk,
                                                 const float* __restrict__ bg2,
                                                 float* __restrict__ out) {
    constexpr int G = 8, NG = 8, LDX = 32;
    __shared__ float sW[128 * 17];  // sW[row][c] = Wstk[row*64+c], c<16; pad 17 vs bank
    __shared__ float smsg[4][128];
    int tid = threadIdx.x;
    for (int i = tid; i < 2048; i += 256) {
        int row = i >> 4, c = i & 15;
        sW[row * 17 + c] = Wstk[row * 64 + c];
    }
    int wid = tid >> 6, lane = tid & 63;
    int n = blockIdx.x * 4 + wid;  // NN % 4 == 0 and grid exact -> n < NN always
    int g = lane / G, q = lane % G;
    h4 EdH = *(const h4*)(aldsEh + (size_t)n * 16 + 8);
    h4 Ed2H = *(const h4*)(aldsEh + (size_t)n * 16 + 12);
    h4 hz = {(f16)0.f, (f16)0.f, (f16)0.f, (f16)0.f};
    h4 acc0 = hz, acc1 = hz, acc2 = hz, acc3 = hz, zH = hz;
    if (g == 0) {  // self loop
        h4 es = *(const h4*)(aldsEh + (size_t)n * 16);
        h4 es2 = *(const h4*)(aldsEh + (size_t)n * 16 + 4);
        h4 xv = *(const h4*)(X + (size_t)n * LDX + q * 4);
        h4 pH = hmax4(es * EdH, es2 * Ed2H);
        zH += pH;
        acc0 += hsplat(pH[0]) * xv;
        acc1 += hsplat(pH[1]) * xv;
        acc2 += hsplat(pH[2]) * xv;
        acc3 += hsplat(pH[3]) * xv;
    }
    int beg = rp[n * RR], end = rp[n * RR + RR];
    int k = beg + g;
    for (; k + NG < end; k += 2 * NG) {
        int s0 = srcs2[k] >> 3, s1 = srcs2[k + NG] >> 3;
        h8 e0 = *(const h8*)(aldsEh + (size_t)s0 * 16);
        h8 e1 = *(const h8*)(aldsEh + (size_t)s1 * 16);
        h4 x0 = *(const h4*)(X + (size_t)s0 * LDX + q * 4);
        h4 x1v = *(const h4*)(X + (size_t)s1 * LDX + q * 4);
        h4 e0lo = {e0[0], e0[1], e0[2], e0[3]};
        h4 e0hi = {e0[4], e0[5], e0[6], e0[7]};
        h4 e1lo = {e1[0], e1[1], e1[2], e1[3]};
        h4 e1hi = {e1[4], e1[5], e1[6], e1[7]};
        h4 p0H = hmax4(e0lo * EdH, e0hi * Ed2H);
        h4 p1H = hmax4(e1lo * EdH, e1hi * Ed2H);
        zH += p0H + p1H;
        acc0 += hsplat(p0H[0]) * x0;
        acc1 += hsplat(p0H[1]) * x0;
        acc2 += hsplat(p0H[2]) * x0;
        acc3 += hsplat(p0H[3]) * x0;
        acc0 += hsplat(p1H[0]) * x1v;
        acc1 += hsplat(p1H[1]) * x1v;
        acc2 += hsplat(p1H[2]) * x1v;
        acc3 += hsplat(p1H[3]) * x1v;
    }
    if (k < end) {
        int s0 = srcs2[k] >> 3;
        h8 e0 = *(const h8*)(aldsEh + (size_t)s0 * 16);
        h4 x0 = *(const h4*)(X + (size_t)s0 * LDX + q * 4);
        h4 e0lo = {e0[0], e0[1], e0[2], e0[3]};
        h4 e0hi = {e0[4], e0[5], e0[6], e0[7]};
        h4 p0H = hmax4(e0lo * EdH, e0hi * Ed2H);
        zH += p0H;
        acc0 += hsplat(p0H[0]) * x0;
        acc1 += hsplat(p0H[1]) * x0;
        acc2 += hsplat(p0H[2]) * x0;
        acc3 += hsplat(p0H[3]) * x0;
    }
    float4 A0 = h4tof4(acc0), A1 = h4tof4(acc1), A2 = h4tof4(acc2), A3 = h4tof4(acc3);
    float4 z = h4tof4(zH);
#pragma unroll
    for (int m = G; m < 64; m <<= 1) {
        red4(A0, m);
        red4(A1, m);
        red4(A2, m);
        red4(A3, m);
        red4(z, m);
    }
    if (g == 0) {  // deposit msg[n][h*32 + q*4 + j] = A_h[j] * iz[h] into LDS
        float4 iz = make_float4(1.f / z.x, 1.f / z.y, 1.f / z.z, 1.f / z.w);
        float* mp = &smsg[wid][q * 4];
        mp[0 * 32 + 0] = A0.x * iz.x; mp[0 * 32 + 1] = A0.y * iz.x;
        mp[0 * 32 + 2] = A0.z * iz.x; mp[0 * 32 + 3] = A0.w * iz.x;
        mp[1 * 32 + 0] = A1.x * iz.y; mp[1 * 32 + 1] = A1.y * iz.y;
        mp[1 * 32 + 2] = A1.z * iz.y; mp[1 * 32 + 3] = A1.w * iz.y;
        mp[2 * 32 + 0] = A2.x * iz.z; mp[2 * 32 + 1] = A2.y * iz.z;
        mp[2 * 32 + 2] = A2.z * iz.z; mp[2 * 32 + 3] = A2.w * iz.z;
        mp[3 * 32 + 0] = A3.x * iz.w; mp[3 * 32 + 1] = A3.y * iz.w;
        mp[3 * 32 + 2] = A3.z * iz.w; mp[3 * 32 + 3] = A3.w * iz.w;
    }
    __syncthreads();
    // Phase 2: thread = (node w, col c, quarter qq); 32 FMA over k = qq*32..qq*32+31
    int w = tid >> 6, idx = tid & 63;
    int c = idx >> 2, qq = idx & 3;
    const float* ms = &smsg[w][qq * 32];
    float s = 0.f;
#pragma unroll
    for (int kk = 0; kk < 32; kk++) s = fmaf(ms[kk], sW[(qq * 32 + kk) * 17 + c], s);
    s += __shfl_xor(s, 1);
    s += __shfl_xor(s, 2);
    if (qq == 0) {
        int nn = blockIdx.x * 4 + w;
        float o = tanhf(fmaxf(0.25f * s + bg2[c], 0.f));
        out[(size_t)nn * 16 + c] = o;
    }
}

extern "C" void kernel_launch(void* const* d_in, const int* in_sizes, int n_in,
                              void* d_out, int out_size, void* d_ws, size_t ws_size,
                              hipStream_t stream) {
    const float* x      = (const float*)d_in[0];
    const int*   ei     = (const int*)d_in[1];
    const int*   et     = (const int*)d_in[2];
    const float* basis1 = (const float*)d_in[3];
    const float* comp1  = (const float*)d_in[4];
    const float* root1  = (const float*)d_in[5];
    const float* brg1   = (const float*)d_in[6];
    const float* wg1    = (const float*)d_in[7];
    const float* asrc1  = (const float*)d_in[8];
    const float* adst1  = (const float*)d_in[9];
    const float* bg1    = (const float*)d_in[10];
    const float* basis2 = (const float*)d_in[11];
    const float* comp2  = (const float*)d_in[12];
    const float* root2  = (const float*)d_in[13];
    const float* brg2   = (const float*)d_in[14];
    const float* wg2    = (const float*)d_in[15];
    const float* asrc2  = (const float*)d_in[16];
    const float* adst2  = (const float*)d_in[17];
    const float* bg2    = (const float*)d_in[18];
    const int* src = ei;
    const int* dst = ei + EE;
    float* out = (float*)d_out;

    // ---- int region ----
    int* wsi = (int*)d_ws;
    size_t ioff = 0;
    auto ialloc = [&](size_t n) { int* p = wsi + ioff; ioff += (n + 3) & ~(size_t)3; return p; };
    int* rp   = ialloc(SEGS + 1);
    int* srcs2 = ialloc(EE);
    int* recbuf = ialloc(EE);
    int* cbcur = ialloc(128);
    int* buccnt = ialloc(128);
    int* bucbase = ialloc(128);
    // ---- float region ----
    float* wsf = (float*)(wsi + ioff);
    size_t total_f = (ws_size - ioff * sizeof(int)) / sizeof(float);
    size_t P_f = (size_t)NN * 320;
    size_t need_f = P_f + (size_t)NN * 128
                  + 40960 + 20480 + 16384 + 8192 + 4096 + 2048
                  + (size_t)NN * 8
                  + 20480 + 8192 + 40960
                  + (size_t)NN * 32 + (size_t)NN * 16 + (size_t)NN * 32 + 64;
    if (total_f < need_f) return;  // loud fail: output stays zero
    size_t foff = 0;
    auto falloc = [&](size_t n) { float* p = wsf + foff; foff += (n + 3) & ~(size_t)3; return p; };
    float* P      = falloc(P_f);
    float* x2     = falloc((size_t)NN * 128);
    float* Wcat2e = falloc(40960);
    float* Wb1    = falloc(20480);
    float* wg1r   = falloc(16384);
    float* Wstk   = falloc(8192);
    float* U1p    = falloc(4096);
    float* U2p    = falloc(2048);
    f16* aldsEh   = (f16*)falloc((size_t)NN * 8);   // [n][16] f16: Es/Es2/Ed/Ed2
    short* Wb1pk  = (short*)falloc(20480);
    short* wg1rpk = (short*)falloc(8192);
    short* Wcatpk = (short*)falloc(40960);
    f16* x1h      = (f16*)falloc((size_t)NN * 32);  // [n][64] fp16 (u-gemm OUTH target)
    f16* x3h      = (f16*)falloc((size_t)NN * 16);  // [n][32] fp16
    f16* xh       = (f16*)falloc((size_t)NN * 32);  // [n][64] fp16 input copy
    f16* Uh = (f16*)P;                   // L1 basis-gather output [n][320] fp16
    f16* x2h = (f16*)x2;                 // [n][128] fp16 (msg1-gemm OUTH target)
    f16* msg1h  = (f16*)P;               // [n][4][64] fp16 (Uh dead after u-gemm)
    float* x3   = P;                     // fp32 root-panel out [n][32] compact
    f16* ybuf3h = (f16*)(P + (size_t)NN * 64);  // L3 rel panels [4][n][64] fp16

    const int NB4 = (NN + 3) / 4;
    const int NB32 = (NN + 31) / 32;

    // ---- CSR build: fused hist+xh -> 98-scan -> binned fillA -> bucket-local fillB2 ----
    hipMemsetAsync(buccnt, 0, 128 * sizeof(int), stream);
    k_histxh<<<EB4 + XB, 256, 0, stream>>>(dst, buccnt, x, xh);
    k_scan98<<<1, 128, 0, stream>>>(buccnt, bucbase, cbcur);
    k_fillA<<<EB4, 256, 0, stream>>>(src, dst, et, cbcur, recbuf);
    k_fillB2<<<NBUK, 256, 0, stream>>>(bucbase, recbuf, rp, srcs2);
    k_prep<<<(92160 + 255) / 256, 256, 0, stream>>>(
        wg1, wg2, root1, root2, basis1, basis2, comp2, asrc1, adst1, asrc2, adst2,
        Wcat2e, wg1r, Wstk, U1p, U2p, Wb1);
    k_pack<<<34, 256, 0, stream>>>(Wb1, wg1r, Wcat2e, Wb1pk, wg1rpk, Wcatpk);

    // ---- layer 1: RGCN(64->64)+relu -> x1h fp16 directly (OUTH) ----
    k_gagg1<<<NB4, 256, 0, stream>>>(rp, srcs2, comp1, xh, Uh);
    k_mfma<320, 64, 2, 1><<<dim3(NTW, 1), 256, 0, stream>>>(Uh, 320, 0, Wb1pk, 0,
                                                            (float*)x1h, 64, 0, brg1, 0);

    // ---- layer 2: GAT(64 -> 4x32 concat): packed fp16 logits+accum; x2h fp16 (OUTH) ----
    k_alds1<<<NB32, 256, 0, stream>>>(x1h, U1p, aldsEh);
    k_gatx64<<<NB4, 256, 0, stream>>>(rp, srcs2, aldsEh, x1h, msg1h);
    k_mfma<64, 32, 0, 1><<<dim3(NTW, 4), 256, 0, stream>>>(msg1h, 256, 64, wg1rpk, 4096,
                                                           (float*)x2h, 128, 32, bg1, 32);

    // ---- layer 3: RGCN(128->32)+relu; L3 MFMA split 6-tiles x 3 y-slices ----
    k_mfmaL3<<<dim3(NTW, 3), 256, 0, stream>>>(x2h, Wcatpk, x3, ybuf3h);
    k_agg2<<<NB4, 256, 0, stream>>>(rp, srcs2, ybuf3h, brg2, U2p, x3, x3h, aldsEh);

    // ---- layer 4: GAT(32 -> 4x16, mean heads) + relu + tanh, final fused via LDS ----
    k_gatx32f<<<NB4, 256, 0, stream>>>(rp, srcs2, aldsEh, x3h, Wstk, bg2, out);
}

// Round 16
// 381.595 us; speedup vs baseline: 1.0279x; 1.0279x over previous
//
#include <hip/hip_runtime.h>
#include <math.h>

#define NN 50000
#define EE 800000
#define RR 8
#define SLOPE 0.2f
#define SEGS (NN * RR)            /* 400000 per-(node,relation) segments */
#define NTW ((NN + 63) / 64)      /* 782 mfma row-tiles (64 rows each) */
#define NBUK 98                   /* coarse buckets: dst>>9 (512 dst values each) */
#define SEGB 4096                 /* segments per bucket = 512 * RR */
#define EB4 ((EE + 4095) / 4096)  /* 196 fillA/hist blocks */
#define XB ((NN * 8 + 255) / 256) /* 1563 xh blocks */

typedef __attribute__((ext_vector_type(4))) float f32x4;
typedef _Float16 f16;
typedef __attribute__((ext_vector_type(4))) _Float16 h4;
typedef __attribute__((ext_vector_type(8))) _Float16 h8;

__device__ __forceinline__ void fmacc(float4& a, const float4& v, float p) {
    a.x = fmaf(v.x, p, a.x);
    a.y = fmaf(v.y, p, a.y);
    a.z = fmaf(v.z, p, a.z);
    a.w = fmaf(v.w, p, a.w);
}

__device__ __forceinline__ void red4(float4& a, int m) {
    a.x += __shfl_xor(a.x, m);
    a.y += __shfl_xor(a.y, m);
    a.z += __shfl_xor(a.z, m);
    a.w += __shfl_xor(a.w, m);
}

__device__ __forceinline__ float4 h4tof4(h4 t) {
    return make_float4((float)t[0], (float)t[1], (float)t[2], (float)t[3]);
}

__device__ __forceinline__ h4 hmax4(h4 a, h4 b) {
    h4 r;
    r[0] = a[0] > b[0] ? a[0] : b[0];
    r[1] = a[1] > b[1] ? a[1] : b[1];
    r[2] = a[2] > b[2] ? a[2] : b[2];
    r[3] = a[3] > b[3] ? a[3] : b[3];
    return r;
}

__device__ __forceinline__ h4 hsplat(f16 s) { return (h4){s, s, s, s}; }

// ============================ CSR build (bucket-local) + fused fp16 x copy ============================
__global__ __launch_bounds__(256) void k_histxh(const int* __restrict__ dst,
                                                int* __restrict__ buccnt,
                                                const float* __restrict__ X,
                                                f16* __restrict__ xh) {
    __shared__ int h[NBUK];
    int b = blockIdx.x;
    int tid = threadIdx.x;
    if (b < EB4) {  // histogram part
        for (int i = tid; i < NBUK; i += 256) h[i] = 0;
        __syncthreads();
        int e0 = b * 4096;
        int cnt = EE - e0;
        if (cnt > 4096) cnt = 4096;
        for (int i = tid; i < cnt; i += 256) atomicAdd(&h[dst[e0 + i] >> 9], 1);
        __syncthreads();
        for (int i = tid; i < NBUK; i += 256)
            if (h[i]) atomicAdd(&buccnt[i], h[i]);
    } else {  // xh part
        int i = (b - EB4) * 256 + tid;
        if (i >= NN * 8) return;
        float4 v0 = *(const float4*)(X + (size_t)i * 8);
        float4 v1 = *(const float4*)(X + (size_t)i * 8 + 4);
        h8 hv = {(f16)v0.x, (f16)v0.y, (f16)v0.z, (f16)v0.w,
                 (f16)v1.x, (f16)v1.y, (f16)v1.z, (f16)v1.w};
        *(h8*)(xh + (size_t)i * 8) = hv;
    }
}

__global__ void k_scan98(const int* __restrict__ buccnt, int* __restrict__ bucbase,
                         int* __restrict__ cbcur) {
    __shared__ int sh[128];
    int t = threadIdx.x;
    int v = (t < NBUK) ? buccnt[t] : 0;
    sh[t] = v;
    __syncthreads();
    for (int off = 1; off < 128; off <<= 1) {
        int u = (t >= off) ? sh[t - off] : 0;
        __syncthreads();
        sh[t] += u;
        __syncthreads();
    }
    int excl = sh[t] - v;
    if (t <= NBUK) bucbase[t] = excl;  // bucbase[NBUK] == EE
    if (t < NBUK) cbcur[t] = excl;
}

// ===== fill phase A: bin edges into recbuf in coarse-bucket-major order =====
__global__ __launch_bounds__(256) void k_fillA(const int* __restrict__ src,
                                               const int* __restrict__ dst,
                                               const int* __restrict__ et,
                                               int* __restrict__ cbcur,
                                               int* __restrict__ recbuf) {
    __shared__ int hist[NBUK], lcur[NBUK], gres[NBUK];
    int tid = threadIdx.x;
    int e0 = blockIdx.x * 4096;
    int cnt = EE - e0;
    if (cnt > 4096) cnt = 4096;
    for (int i = tid; i < NBUK; i += 256) { hist[i] = 0; lcur[i] = 0; }
    __syncthreads();
    int myb[16], myrec[16];
#pragma unroll
    for (int j = 0; j < 16; j++) {
        int i = tid + j * 256;
        if (i < cnt) {
            int e = e0 + i;
            int d = dst[e];
            int b = d >> 9;
            myb[j] = b;
            myrec[j] = ((d & 511) << 19) | (src[e] << 3) | et[e];
            atomicAdd(&hist[b], 1);
        } else {
            myb[j] = -1;
            myrec[j] = 0;
        }
    }
    __syncthreads();
    if (tid < NBUK) gres[tid] = atomicAdd(&cbcur[tid], hist[tid]);
    __syncthreads();
#pragma unroll
    for (int j = 0; j < 16; j++) {
        if (myb[j] >= 0) {
            int p = atomicAdd(&lcur[myb[j]], 1);
            recbuf[gres[myb[j]] + p] = myrec[j];
        }
    }
}

// ===== fill phase B2: one block per bucket; counts+scan+rp-write+scatter in LDS =====
__global__ __launch_bounds__(256) void k_fillB2(const int* __restrict__ bucbase,
                                                const int* __restrict__ recbuf,
                                                int* __restrict__ rp,
                                                int* __restrict__ srcs2) {
    __shared__ int cnt[SEGB];
    __shared__ int psc[256];
    int b = blockIdx.x;
    int segbase = b * SEGB;
    int nseg = SEGS - segbase;
    if (nseg > SEGB) nseg = SEGB;
    int base = bucbase[b];
    int cntE = bucbase[b + 1] - base;
    int tid = threadIdx.x;
    for (int s = tid; s < SEGB; s += 256) cnt[s] = 0;
    __syncthreads();
    for (int i = tid; i < cntE; i += 256) {
        int rec = recbuf[base + i];
        int segl = ((rec >> 19) << 3) | (rec & 7);
        atomicAdd(&cnt[segl], 1);
    }
    __syncthreads();
    int loc[16];
    int sbase = tid * 16;
    int run = 0;
#pragma unroll
    for (int j = 0; j < 16; j++) { loc[j] = cnt[sbase + j]; run += loc[j]; }
    psc[tid] = run;
    __syncthreads();
    for (int off = 1; off < 256; off <<= 1) {
        int u = (tid >= off) ? psc[tid - off] : 0;
        __syncthreads();
        psc[tid] += u;
        __syncthreads();
    }
    int excl = psc[tid] - run;
#pragma unroll
    for (int j = 0; j < 16; j++) {
        int s = sbase + j;
        int v = loc[j];
        cnt[s] = excl;
        if (s < nseg) rp[segbase + s] = base + excl;
        excl += v;
    }
    __syncthreads();
    for (int i = tid; i < cntE; i += 256) {
        int rec = recbuf[base + i];
        int segl = ((rec >> 19) << 3) | (rec & 7);
        int p = atomicAdd(&cnt[segl], 1);
        srcs2[base + p] = rec & 0x7FFFF;
    }
    if (b == NBUK - 1 && tid == 0) rp[SEGS] = EE;
}

// ==== prep (merged): padded weights, logit projections, stacked Wb1, Wcat2e compose ====
__global__ void k_prep(const float* __restrict__ wg1, const float* __restrict__ wg2,
                       const float* __restrict__ root1, const float* __restrict__ root2,
                       const float* __restrict__ basis1, const float* __restrict__ basis2,
                       const float* __restrict__ comp2,
                       const float* __restrict__ asrc1, const float* __restrict__ adst1,
                       const float* __restrict__ asrc2, const float* __restrict__ adst2,
                       float* __restrict__ Wcat2e, float* __restrict__ wg1r,
                       float* __restrict__ Wstk, float* __restrict__ U1p,
                       float* __restrict__ U2p, float* __restrict__ Wb1) {
    int idx = blockIdx.x * 256 + threadIdx.x;
    if (idx < 16384) {  // wg1r[h][k][c] (c<32 valid)
        int h = idx >> 12, kc = idx & 4095;
        int k = kc >> 6, c = kc & 63;
        wg1r[idx] = (c < 32) ? wg1[k * 128 + h * 32 + c] : 0.f;
    } else if (idx < 24576) {  // Wstk[h*32+k][c] = wg2[k][h*16+c] (c<16 valid)
        int j = idx - 16384;
        int row = j >> 6, c = j & 63;
        int h = row >> 5, k = row & 31;
        Wstk[j] = (c < 16) ? wg2[k * 64 + h * 16 + c] : 0.f;
    } else if (idx < 32768) {  // Wcat2e root block: [128][col 0-63] = root2 zero-padded
        int j = idx - 24576;
        int k = j >> 6, c = j & 63;
        Wcat2e[k * 320 + c] = (c < 32) ? root2[k * 32 + c] : 0.f;
    } else if (idx < 36864) {  // U1p[k][j]
        int j0 = idx - 32768;
        int k = j0 >> 6, j = j0 & 63;
        float s = 0.f;
        if (j < 8) {
            int h = j & 3;
            const float* a = (j < 4) ? asrc1 : adst1;
            for (int c = 0; c < 32; c++) s += wg1[k * 128 + h * 32 + c] * a[h * 32 + c];
        }
        U1p[j0] = s;
    } else if (idx < 38912) {  // U2p[k][j]
        int j0 = idx - 36864;
        int k = j0 >> 6, j = j0 & 63;
        float s = 0.f;
        if (j < 8) {
            int h = j & 3;
            const float* a = (j < 4) ? asrc2 : adst2;
            for (int c = 0; c < 16; c++) s += wg2[k * 64 + h * 16 + c] * a[h * 16 + c];
        }
        U2p[j0] = s;
    } else if (idx < 55296) {  // Wb1 rows 0-255 = basis1 flat copy
        Wb1[idx - 38912] = basis1[idx - 38912];
    } else if (idx < 59392) {  // Wb1 rows 256-319 = root1
        Wb1[idx - 38912] = root1[idx - 55296];
    } else if (idx < 92160) {  // Wcat2e basis-composed block: [128][col 64-319]
        int j = idx - 59392;
        int i = j >> 8, rc = j & 255;
        int r = rc >> 5, o = rc & 31;
        float acc = 0.f;
#pragma unroll
        for (int b = 0; b < 4; b++) acc += comp2[r * 4 + b] * basis2[b * 4096 + i * 32 + o];
        Wcat2e[i * 320 + 64 + rc] = acc;
    }
}

// ==== pack weights into fp16 hi/lo MFMA fragment order (A is fp16 -> native f16 MFMA) ====
__global__ void k_pack(const float* __restrict__ Wb1, const float* __restrict__ wg1r,
                       const float* __restrict__ Wcat, short* __restrict__ pWb1,
                       short* __restrict__ pwg1r, short* __restrict__ pWcat) {
    int u = blockIdx.x * 256 + threadIdx.x;
    int lane = u & 63, pair = u >> 6;
    if (pair >= 136) return;
    int m = lane & 15, g = lane >> 4;
    const float* src;
    int ldB, col, k0;
    short* dst;
    if (pair < 40) {
        int ct = pair / 10, kc = pair % 10;
        src = Wb1; ldB = 64; col = ct * 16 + m; k0 = kc * 32 + g * 8;
        dst = pWb1 + pair * 1024 + lane * 8;
    } else if (pair < 56) {
        int q = pair - 40;
        int h = q >> 2, lp = q & 3, ct = lp >> 1, kc = lp & 1;
        src = wg1r + h * 4096; ldB = 64; col = ct * 16 + m; k0 = kc * 32 + g * 8;
        dst = pwg1r + q * 1024 + lane * 8;
    } else {
        int q = pair - 56;
        int p = q >> 4, lp = q & 15, ct = lp >> 2, kc = lp & 3;
        src = Wcat; ldB = 320; col = p * 64 + ct * 16 + m; k0 = kc * 32 + g * 8;
        dst = pWcat + q * 1024 + lane * 8;
    }
    h8 H, L;
#pragma unroll
    for (int r = 0; r < 8; r++) {
        float e = src[(size_t)(k0 + r) * ldB + col];
        f16 hi = (f16)e;
        H[r] = hi;
        L[r] = (f16)(e - (float)hi);
    }
    *(h8*)dst = H;
    *(h8*)(dst + 512) = L;
}

// ============ MFMA GEMM (fp16 A, fp16 hi/lo B, 2-term): 4 waves x 16 rows, NCOL cols ============
template <int KTOT, int NCOL, int ACT = 0, int OUTH = 0>
__global__ __launch_bounds__(256) void k_mfma(const f16* __restrict__ X, int ldX, int xmb,
                                              const short* __restrict__ Bpk, int bmb,
                                              float* __restrict__ Y, int ldY, size_t ymb,
                                              const float* __restrict__ bias, int biasmb) {
    constexpr int NKC = KTOT / 32;
    constexpr int NCT = NCOL / 16;
    const int tid = threadIdx.x;
    const int wid = tid >> 6, lane = tid & 63;
    const int m = lane & 15, g = lane >> 4;
    const int mb = blockIdx.y;
    const int rowbase = blockIdx.x * 64 + wid * 16;
    if (rowbase >= NN) return;  // NN % 16 == 0: per-wave all-or-nothing
    const f16* Xm = X + (size_t)mb * xmb + (size_t)(rowbase + m) * ldX;
    const short* Bm = Bpk + (size_t)mb * bmb;

    f32x4 acc[NCT];
#pragma unroll
    for (int c = 0; c < NCT; c++) acc[c] = (f32x4){0.f, 0.f, 0.f, 0.f};

#pragma unroll
    for (int kc = 0; kc < NKC; kc++) {
        h8 av = *(const h8*)(Xm + kc * 32 + g * 8);
#pragma unroll
        for (int ct = 0; ct < NCT; ct++) {
            const short* bp = Bm + (size_t)(ct * NKC + kc) * 1024 + lane * 8;
            h8 bh = *(const h8*)bp;
            h8 bl = *(const h8*)(bp + 512);
            acc[ct] = __builtin_amdgcn_mfma_f32_16x16x32_f16(av, bh, acc[ct], 0, 0, 0);
            acc[ct] = __builtin_amdgcn_mfma_f32_16x16x32_f16(av, bl, acc[ct], 0, 0, 0);
        }
    }

#pragma unroll
    for (int ct = 0; ct < NCT; ct++) {
        int col = ct * 16 + m;
        float bv = bias ? bias[mb * biasmb + col] : 0.f;
#pragma unroll
        for (int i = 0; i < 4; i++) {
            float o = acc[ct][i] + bv;
            if (ACT == 2) o = fmaxf(o, 0.f);
            if (OUTH) {
                f16* Yh = (f16*)Y;
                Yh[(size_t)mb * ymb + (size_t)(rowbase + g * 4 + i) * ldY + col] = (f16)o;
            } else {
                Y[(size_t)mb * ymb + (size_t)(rowbase + g * 4 + i) * ldY + col] = o;
            }
        }
    }
}

// ===== L3 transform: 18 live col-tiles split 6-per-blockIdx.y (fp16 2-term MFMA) =====
__global__ __launch_bounds__(256) void k_mfmaL3(const f16* __restrict__ Xh,
                                                const short* __restrict__ Bpk,
                                                float* __restrict__ x3,
                                                f16* __restrict__ ybuf3h) {
    const int tid = threadIdx.x;
    const int wid = tid >> 6, lane = tid & 63;
    const int m = lane & 15, g = lane >> 4;
    const int y = blockIdx.y;
    const int rowbase = blockIdx.x * 64 + wid * 16;
    if (rowbase >= NN) return;
    const f16* Xm = Xh + (size_t)(rowbase + m) * 128;

    f32x4 acc[6];
#pragma unroll
    for (int j = 0; j < 6; j++) acc[j] = (f32x4){0.f, 0.f, 0.f, 0.f};

#pragma unroll
    for (int kc = 0; kc < 4; kc++) {
        h8 av = *(const h8*)(Xm + kc * 32 + g * 8);
#pragma unroll
        for (int j = 0; j < 6; j++) {
            int bct = (y == 0) ? ((j < 2) ? j : j + 2) : (8 + (y - 1) * 6 + j);
            const short* bp = Bpk + (size_t)(bct * 4 + kc) * 1024 + lane * 8;
            h8 bh = *(const h8*)bp;
            h8 bl = *(const h8*)(bp + 512);
            acc[j] = __builtin_amdgcn_mfma_f32_16x16x32_f16(av, bh, acc[j], 0, 0, 0);
            acc[j] = __builtin_amdgcn_mfma_f32_16x16x32_f16(av, bl, acc[j], 0, 0, 0);
        }
    }
#pragma unroll
    for (int j = 0; j < 6; j++) {
        int bct = (y == 0) ? ((j < 2) ? j : j + 2) : (8 + (y - 1) * 6 + j);
        if (bct < 2) {  // root cols 0-31 -> x3 fp32 compact [n][32]
            int col = bct * 16 + m;
#pragma unroll
            for (int r = 0; r < 4; r++) {
                int n = rowbase + g * 4 + r;
                x3[(size_t)n * 32 + col] = acc[j][r];
            }
        } else {  // rel col gcol = bct*16+m-64 -> panel p, col cc (fp16)
            int gcol = bct * 16 + m - 64;
            int p = gcol >> 6, cc = gcol & 63;
            f16* Yp = ybuf3h + (size_t)p * NN * 64;
#pragma unroll
            for (int r = 0; r < 4; r++) {
                int n = rowbase + g * 4 + r;
                Yp[(size_t)n * 64 + cc] = (f16)acc[j][r];
            }
        }
    }
}

// ===== L1 basis-space gather: packed-fp16 accumulation; U[n][b][64]; U[n][4][64]=x[n] =====
__global__ __launch_bounds__(256) void k_gagg1(const int* __restrict__ rp,
                                               const int* __restrict__ srcs2,
                                               const float* __restrict__ comp,
                                               const f16* __restrict__ Xh,
                                               f16* __restrict__ Uh) {
    __shared__ h4 sh_w[4][8];
    int wid = threadIdx.x >> 6, lane = threadIdx.x & 63;
    int n = blockIdx.x * 4 + wid;
    int rpv = (lane <= 8) ? rp[n * RR + lane] : 0;
    int nxt = __shfl(rpv, (lane + 1) & 63);
    if (lane < 8) {
        float inv = 1.f / (float)((nxt - rpv) > 0 ? (nxt - rpv) : 1);
        float4 c = *(const float4*)(comp + lane * 4);
        sh_w[wid][lane] = (h4){(f16)(c.x * inv), (f16)(c.y * inv),
                               (f16)(c.z * inv), (f16)(c.w * inv)};
    }
    int q = lane & 15;
    int beg = rp[n * RR], end = rp[n * RR + RR];
    h4 hz = {(f16)0.f, (f16)0.f, (f16)0.f, (f16)0.f};
    h4 a0 = hz, a1 = hz, a2 = hz, a3 = hz;
    int k = beg + (lane >> 4);
    for (; k + 4 < end; k += 8) {
        int key0 = srcs2[k], key1 = srcs2[k + 4];
        h4 w0 = sh_w[wid][key0 & 7], w1 = sh_w[wid][key1 & 7];
        h4 v0 = *(const h4*)(Xh + (size_t)(key0 >> 3) * 64 + q * 4);
        h4 v1 = *(const h4*)(Xh + (size_t)(key1 >> 3) * 64 + q * 4);
        a0 += hsplat(w0[0]) * v0;
        a1 += hsplat(w0[1]) * v0;
        a2 += hsplat(w0[2]) * v0;
        a3 += hsplat(w0[3]) * v0;
        a0 += hsplat(w1[0]) * v1;
        a1 += hsplat(w1[1]) * v1;
        a2 += hsplat(w1[2]) * v1;
        a3 += hsplat(w1[3]) * v1;
    }
    if (k < end) {
        int key0 = srcs2[k];
        h4 w0 = sh_w[wid][key0 & 7];
        h4 v0 = *(const h4*)(Xh + (size_t)(key0 >> 3) * 64 + q * 4);
        a0 += hsplat(w0[0]) * v0;
        a1 += hsplat(w0[1]) * v0;
        a2 += hsplat(w0[2]) * v0;
        a3 += hsplat(w0[3]) * v0;
    }
    float4 A0 = h4tof4(a0), A1 = h4tof4(a1), A2 = h4tof4(a2), A3 = h4tof4(a3);
    red4(A0, 16); red4(A0, 32);
    red4(A1, 16); red4(A1, 32);
    red4(A2, 16); red4(A2, 32);
    red4(A3, 16); red4(A3, 32);
    if (lane < 16) {
        f16* un = Uh + (size_t)n * 320;
        h4 o0 = {(f16)A0.x, (f16)A0.y, (f16)A0.z, (f16)A0.w};
        h4 o1 = {(f16)A1.x, (f16)A1.y, (f16)A1.z, (f16)A1.w};
        h4 o2 = {(f16)A2.x, (f16)A2.y, (f16)A2.z, (f16)A2.w};
        h4 o3 = {(f16)A3.x, (f16)A3.y, (f16)A3.z, (f16)A3.w};
        *(h4*)(un + 0 * 64 + q * 4) = o0;
        *(h4*)(un + 1 * 64 + q * 4) = o1;
        *(h4*)(un + 2 * 64 + q * 4) = o2;
        *(h4*)(un + 3 * 64 + q * 4) = o3;
        *(h4*)(un + 256 + q * 4) = *(const h4*)(Xh + (size_t)n * 64 + q * 4);
    }
}

// ===== skinny matvec on fp16 x1h + fp16 exp-logit emit =====
__global__ __launch_bounds__(256) void k_alds1(const f16* __restrict__ X1h,
                                               const float* __restrict__ U1p,
                                               f16* __restrict__ aldsEh) {
    __shared__ float sUT[8 * 68];
    int tid = threadIdx.x;
    for (int i = tid; i < 512; i += 256) {
        int j = i >> 6, c = i & 63;
        sUT[j * 68 + c] = U1p[c * 64 + j];
    }
    __syncthreads();
    int lane = tid & 63, wid = tid >> 6;
    int n = blockIdx.x * 32 + wid * 8 + (lane >> 3);
    int q = lane & 7;
    float x[8];
    if (n < NN) {
        h8 hv = *(const h8*)(X1h + (size_t)n * 64 + q * 8);
#pragma unroll
        for (int c = 0; c < 8; c++) x[c] = (float)hv[c];
    } else {
#pragma unroll
        for (int c = 0; c < 8; c++) x[c] = 0.f;
    }
    float al[8];
#pragma unroll
    for (int j = 0; j < 8; j++) {
        const float* u = &sUT[j * 68 + q * 8];
        float s = 0.f;
#pragma unroll
        for (int c = 0; c < 8; c++) s += x[c] * u[c];
        al[j] = s;
    }
#pragma unroll
    for (int m = 1; m < 8; m <<= 1)
#pragma unroll
        for (int j = 0; j < 8; j++) al[j] += __shfl_xor(al[j], m);
    if (n < NN) {
        float av = al[q];
        int pos = (q < 4) ? q : q + 4;  // Es 0-3, Es2 4-7, Ed 8-11, Ed2 12-15
        aldsEh[(size_t)n * 16 + pos] = (f16)__expf(av);
        aldsEh[(size_t)n * 16 + pos + 4] = (f16)__expf(SLOPE * av);
    }
}

// ===== skinny final: msg2 fp16 input =====
__global__ __launch_bounds__(256) void k_final(const f16* __restrict__ Xm,
                                               const float* __restrict__ Wstk,
                                               const float* __restrict__ bg2,
                                               float* __restrict__ out) {
    __shared__ float sWT[16 * 132];
    int tid = threadIdx.x;
    for (int i = tid; i < 2048; i += 256) {
        int c = i >> 7, k = i & 127;
        sWT[c * 132 + k] = Wstk[k * 64 + c];
    }
    __syncthreads();
    int lane = tid & 63, wid = tid >> 6;
    int n = blockIdx.x * 32 + wid * 8 + (lane >> 3);
    int q = lane & 7;
    float x[16];
    if (n < NN) {
#pragma unroll
        for (int t = 0; t < 4; t++) {
            float4 v = h4tof4(*(const h4*)(Xm + (size_t)n * 128 + t * 32 + q * 4));
            x[t * 4 + 0] = v.x; x[t * 4 + 1] = v.y; x[t * 4 + 2] = v.z; x[t * 4 + 3] = v.w;
        }
    } else {
#pragma unroll
        for (int k = 0; k < 16; k++) x[k] = 0.f;
    }
    float al[16];
#pragma unroll
    for (int c = 0; c < 16; c++) {
        float s = 0.f;
#pragma unroll
        for (int t = 0; t < 4; t++) {
            const float* w = &sWT[c * 132 + t * 32 + q * 4];
            s += x[t * 4 + 0] * w[0] + x[t * 4 + 1] * w[1] + x[t * 4 + 2] * w[2] +
                 x[t * 4 + 3] * w[3];
        }
        al[c] = s;
    }
#pragma unroll
    for (int m = 1; m < 8; m <<= 1)
#pragma unroll
        for (int c = 0; c < 16; c++) al[c] += __shfl_xor(al[c], m);
    if (n < NN && q < 4) {
        float4 bv = *(const float4*)(bg2 + q * 4);
        float4 v;
        v.x = tanhf(fmaxf(0.25f * al[q * 4 + 0] + bv.x, 0.f));
        v.y = tanhf(fmaxf(0.25f * al[q * 4 + 1] + bv.y, 0.f));
        v.z = tanhf(fmaxf(0.25f * al[q * 4 + 2] + bv.z, 0.f));
        v.w = tanhf(fmaxf(0.25f * al[q * 4 + 3] + bv.w, 0.f));
        *(float4*)(out + (size_t)n * 16 + q * 4) = v;
    }
}

// ===== aggregate 2 + fused fp16 exp-logit emit (x3prev compact [n][32] fp32) =====
__global__ __launch_bounds__(256) void k_agg2(const int* __restrict__ rp,
                                              const int* __restrict__ srcs2,
                                              const f16* __restrict__ y,
                                              const float* __restrict__ bias,
                                              const float* __restrict__ U2p,
                                              const float* __restrict__ x3prev,
                                              f16* __restrict__ x3h,
                                              f16* __restrict__ aldsEh) {
    __shared__ float sh_inv[4][8];
    int wid = threadIdx.x >> 6, lane = threadIdx.x & 63;
    int n = blockIdx.x * 4 + wid;
    int rpv = (lane <= 8) ? rp[n * RR + lane] : 0;
    int nxt = __shfl(rpv, (lane + 1) & 63);
    if (lane < 8) sh_inv[wid][lane] = 1.f / (float)((nxt - rpv) > 0 ? (nxt - rpv) : 1);
    int q = lane & 7;
    int beg = rp[n * RR], end = rp[n * RR + RR];
    float4 acc = make_float4(0.f, 0.f, 0.f, 0.f);
    int k = beg + (lane >> 3);
    for (; k + 8 < end; k += 16) {
        int key0 = srcs2[k], key1 = srcs2[k + 8];
        int s0 = key0 >> 3, s1 = key1 >> 3;
        int g0 = key0 & 7, g1 = key1 & 7;
        float e0 = sh_inv[wid][g0], e1 = sh_inv[wid][g1];
        float4 v0 = h4tof4(*(const h4*)(y + ((size_t)(g0 >> 1) * NN + s0) * 64 + (g0 & 1) * 32 + q * 4));
        float4 v1 = h4tof4(*(const h4*)(y + ((size_t)(g1 >> 1) * NN + s1) * 64 + (g1 & 1) * 32 + q * 4));
        fmacc(acc, v0, e0);
        fmacc(acc, v1, e1);
    }
    if (k < end) {
        int key0 = srcs2[k];
        int s0 = key0 >> 3;
        int g0 = key0 & 7;
        float4 v0 = h4tof4(*(const h4*)(y + ((size_t)(g0 >> 1) * NN + s0) * 64 + (g0 & 1) * 32 + q * 4));
        fmacc(acc, v0, sh_inv[wid][g0]);
    }
    red4(acc, 8);
    red4(acc, 16);
    red4(acc, 32);
    if (lane < 8) {
        float4 prev = *(const float4*)(x3prev + (size_t)n * 32 + q * 4);
        float4 b = *(const float4*)(bias + q * 4);
        float4 v;
        v.x = fmaxf(prev.x + acc.x + b.x, 0.f);
        v.y = fmaxf(prev.y + acc.y + b.y, 0.f);
        v.z = fmaxf(prev.z + acc.z + b.z, 0.f);
        v.w = fmaxf(prev.w + acc.w + b.w, 0.f);
        h4 hv = {(f16)v.x, (f16)v.y, (f16)v.z, (f16)v.w};
        *(h4*)(x3h + (size_t)n * 32 + q * 4) = hv;
        float al[8];
#pragma unroll
        for (int j = 0; j < 8; j++) {
            al[j] = fmaf(v.x, U2p[(q * 4 + 0) * 64 + j],
                    fmaf(v.y, U2p[(q * 4 + 1) * 64 + j],
                    fmaf(v.z, U2p[(q * 4 + 2) * 64 + j],
                         v.w * U2p[(q * 4 + 3) * 64 + j])));
        }
#pragma unroll
        for (int m = 1; m < 8; m <<= 1) {
#pragma unroll
            for (int j = 0; j < 8; j++) al[j] += __shfl_xor(al[j], m);
        }
        float av = al[q];
        int pos = (q < 4) ? q : q + 4;
        aldsEh[(size_t)n * 16 + pos] = (f16)__expf(av);
        aldsEh[(size_t)n * 16 + pos + 4] = (f16)__expf(SLOPE * av);
    }
}

// ===== fused GAT aggregation: packed-fp16 logits AND accumulation =====
// acc/z in fp16 (bounded: logits ~ +/-0.5 -> p in [0.6,1.7], z <= ~30, msg sums O(10)).
template <int F, int LDX = F>
__global__ __launch_bounds__(256) void k_gatx(const int* __restrict__ rp,
                                              const int* __restrict__ srcs2,
                                              const f16* __restrict__ aldsEh,
                                              const f16* __restrict__ X,
                                              f16* __restrict__ msg) {
    constexpr int G = F / 4;    // lanes per edge-group (16 or 8)
    constexpr int NG = 64 / G;  // groups per wave (4 or 8)
    int wid = threadIdx.x >> 6, lane = threadIdx.x & 63;
    int n = blockIdx.x * 4 + wid;
    if (n >= NN) return;
    int g = lane / G, q = lane % G;
    h4 EdH = *(const h4*)(aldsEh + (size_t)n * 16 + 8);
    h4 Ed2H = *(const h4*)(aldsEh + (size_t)n * 16 + 12);
    h4 hz = {(f16)0.f, (f16)0.f, (f16)0.f, (f16)0.f};
    h4 acc0 = hz, acc1 = hz, acc2 = hz, acc3 = hz, zH = hz;
    if (g == 0) {  // self loop
        h4 es = *(const h4*)(aldsEh + (size_t)n * 16);
        h4 es2 = *(const h4*)(aldsEh + (size_t)n * 16 + 4);
        h4 xv = *(const h4*)(X + (size_t)n * LDX + q * 4);
        h4 pH = hmax4(es * EdH, es2 * Ed2H);
        zH += pH;
        acc0 += hsplat(pH[0]) * xv;
        acc1 += hsplat(pH[1]) * xv;
        acc2 += hsplat(pH[2]) * xv;
        acc3 += hsplat(pH[3]) * xv;
    }
    int beg = rp[n * RR], end = rp[n * RR + RR];
    int k = beg + g;
    for (; k + NG < end; k += 2 * NG) {
        int s0 = srcs2[k] >> 3, s1 = srcs2[k + NG] >> 3;
        h8 e0 = *(const h8*)(aldsEh + (size_t)s0 * 16);
        h8 e1 = *(const h8*)(aldsEh + (size_t)s1 * 16);
        h4 x0 = *(const h4*)(X + (size_t)s0 * LDX + q * 4);
        h4 x1v = *(const h4*)(X + (size_t)s1 * LDX + q * 4);
        h4 e0lo = {e0[0], e0[1], e0[2], e0[3]};
        h4 e0hi = {e0[4], e0[5], e0[6], e0[7]};
        h4 e1lo = {e1[0], e1[1], e1[2], e1[3]};
        h4 e1hi = {e1[4], e1[5], e1[6], e1[7]};
        h4 p0H = hmax4(e0lo * EdH, e0hi * Ed2H);
        h4 p1H = hmax4(e1lo * EdH, e1hi * Ed2H);
        zH += p0H + p1H;
        acc0 += hsplat(p0H[0]) * x0;
        acc1 += hsplat(p0H[1]) * x0;
        acc2 += hsplat(p0H[2]) * x0;
        acc3 += hsplat(p0H[3]) * x0;
        acc0 += hsplat(p1H[0]) * x1v;
        acc1 += hsplat(p1H[1]) * x1v;
        acc2 += hsplat(p1H[2]) * x1v;
        acc3 += hsplat(p1H[3]) * x1v;
    }
    if (k < end) {
        int s0 = srcs2[k] >> 3;
        h8 e0 = *(const h8*)(aldsEh + (size_t)s0 * 16);
        h4 x0 = *(const h4*)(X + (size_t)s0 * LDX + q * 4);
        h4 e0lo = {e0[0], e0[1], e0[2], e0[3]};
        h4 e0hi = {e0[4], e0[5], e0[6], e0[7]};
        h4 p0H = hmax4(e0lo * EdH, e0hi * Ed2H);
        zH += p0H;
        acc0 += hsplat(p0H[0]) * x0;
        acc1 += hsplat(p0H[1]) * x0;
        acc2 += hsplat(p0H[2]) * x0;
        acc3 += hsplat(p0H[3]) * x0;
    }
    float4 A0 = h4tof4(acc0), A1 = h4tof4(acc1), A2 = h4tof4(acc2), A3 = h4tof4(acc3);
    float4 z = h4tof4(zH);
#pragma unroll
    for (int m = G; m < 64; m <<= 1) {
        red4(A0, m);
        red4(A1, m);
        red4(A2, m);
        red4(A3, m);
        red4(z, m);
    }
    if (g == 0) {
        float4 iz = make_float4(1.f / z.x, 1.f / z.y, 1.f / z.z, 1.f / z.w);
        f16* mp = msg + (size_t)n * 4 * F + q * 4;
        h4 o0 = {(f16)(A0.x * iz.x), (f16)(A0.y * iz.x), (f16)(A0.z * iz.x), (f16)(A0.w * iz.x)};
        h4 o1 = {(f16)(A1.x * iz.y), (f16)(A1.y * iz.y), (f16)(A1.z * iz.y), (f16)(A1.w * iz.y)};
        h4 o2 = {(f16)(A2.x * iz.z), (f16)(A2.y * iz.z), (f16)(A2.z * iz.z), (f16)(A2.w * iz.z)};
        h4 o3 = {(f16)(A3.x * iz.w), (f16)(A3.y * iz.w), (f16)(A3.z * iz.w), (f16)(A3.w * iz.w)};
        *(h4*)(mp + 0 * F) = o0;
        *(h4*)(mp + 1 * F) = o1;
        *(h4*)(mp + 2 * F) = o2;
        *(h4*)(mp + 3 * F) = o3;
    }
}

extern "C" void kernel_launch(void* const* d_in, const int* in_sizes, int n_in,
                              void* d_out, int out_size, void* d_ws, size_t ws_size,
                              hipStream_t stream) {
    const float* x      = (const float*)d_in[0];
    const int*   ei     = (const int*)d_in[1];
    const int*   et     = (const int*)d_in[2];
    const float* basis1 = (const float*)d_in[3];
    const float* comp1  = (const float*)d_in[4];
    const float* root1  = (const float*)d_in[5];
    const float* brg1   = (const float*)d_in[6];
    const float* wg1    = (const float*)d_in[7];
    const float* asrc1  = (const float*)d_in[8];
    const float* adst1  = (const float*)d_in[9];
    const float* bg1    = (const float*)d_in[10];
    const float* basis2 = (const float*)d_in[11];
    const float* comp2  = (const float*)d_in[12];
    const float* root2  = (const float*)d_in[13];
    const float* brg2   = (const float*)d_in[14];
    const float* wg2    = (const float*)d_in[15];
    const float* asrc2  = (const float*)d_in[16];
    const float* adst2  = (const float*)d_in[17];
    const float* bg2    = (const float*)d_in[18];
    const int* src = ei;
    const int* dst = ei + EE;
    float* out = (float*)d_out;

    // ---- int region ----
    int* wsi = (int*)d_ws;
    size_t ioff = 0;
    auto ialloc = [&](size_t n) { int* p = wsi + ioff; ioff += (n + 3) & ~(size_t)3; return p; };
    int* rp   = ialloc(SEGS + 1);
    int* srcs2 = ialloc(EE);
    int* recbuf = ialloc(EE);
    int* cbcur = ialloc(128);
    int* buccnt = ialloc(128);
    int* bucbase = ialloc(128);
    // ---- float region ----
    float* wsf = (float*)(wsi + ioff);
    size_t total_f = (ws_size - ioff * sizeof(int)) / sizeof(float);
    size_t P_f = (size_t)NN * 320;
    size_t need_f = P_f + (size_t)NN * 128
                  + 40960 + 20480 + 16384 + 8192 + 4096 + 2048
                  + (size_t)NN * 8
                  + 20480 + 8192 + 40960
                  + (size_t)NN * 32 + (size_t)NN * 16 + (size_t)NN * 32 + 64;
    if (total_f < need_f) return;  // loud fail: output stays zero
    size_t foff = 0;
    auto falloc = [&](size_t n) { float* p = wsf + foff; foff += (n + 3) & ~(size_t)3; return p; };
    float* P      = falloc(P_f);
    float* x2     = falloc((size_t)NN * 128);
    float* Wcat2e = falloc(40960);
    float* Wb1    = falloc(20480);
    float* wg1r   = falloc(16384);
    float* Wstk   = falloc(8192);
    float* U1p    = falloc(4096);
    float* U2p    = falloc(2048);
    f16* aldsEh   = (f16*)falloc((size_t)NN * 8);   // [n][16] f16: Es/Es2/Ed/Ed2
    short* Wb1pk  = (short*)falloc(20480);
    short* wg1rpk = (short*)falloc(8192);
    short* Wcatpk = (short*)falloc(40960);
    f16* x1h      = (f16*)falloc((size_t)NN * 32);  // [n][64] fp16 (u-gemm OUTH target)
    f16* x3h      = (f16*)falloc((size_t)NN * 16);  // [n][32] fp16
    f16* xh       = (f16*)falloc((size_t)NN * 32);  // [n][64] fp16 input copy
    f16* Uh = (f16*)P;                   // L1 basis-gather output [n][320] fp16
    f16* x2h = (f16*)x2;                 // [n][128] fp16 (msg1-gemm OUTH target)
    f16* msg1h  = (f16*)P;               // [n][4][64] fp16 (Uh dead after u-gemm)
    float* x3   = P;                     // fp32 root-panel out [n][32] compact
    f16* ybuf3h = (f16*)(P + (size_t)NN * 64);  // L3 rel panels [4][n][64] fp16
    f16* msg2h  = (f16*)(P + (size_t)NN * 64);  // [n][4][32] fp16 (ybuf3h dead after agg2)

    const int NB4 = (NN + 3) / 4;
    const int NB32 = (NN + 31) / 32;

    // ---- CSR build: fused hist+xh -> 98-scan -> binned fillA -> bucket-local fillB2 ----
    hipMemsetAsync(buccnt, 0, 128 * sizeof(int), stream);
    k_histxh<<<EB4 + XB, 256, 0, stream>>>(dst, buccnt, x, xh);
    k_scan98<<<1, 128, 0, stream>>>(buccnt, bucbase, cbcur);
    k_fillA<<<EB4, 256, 0, stream>>>(src, dst, et, cbcur, recbuf);
    k_fillB2<<<NBUK, 256, 0, stream>>>(bucbase, recbuf, rp, srcs2);
    k_prep<<<(92160 + 255) / 256, 256, 0, stream>>>(
        wg1, wg2, root1, root2, basis1, basis2, comp2, asrc1, adst1, asrc2, adst2,
        Wcat2e, wg1r, Wstk, U1p, U2p, Wb1);
    k_pack<<<34, 256, 0, stream>>>(Wb1, wg1r, Wcat2e, Wb1pk, wg1rpk, Wcatpk);

    // ---- layer 1: RGCN(64->64)+relu -> x1h fp16 directly (OUTH) ----
    k_gagg1<<<NB4, 256, 0, stream>>>(rp, srcs2, comp1, xh, Uh);
    k_mfma<320, 64, 2, 1><<<dim3(NTW, 1), 256, 0, stream>>>(Uh, 320, 0, Wb1pk, 0,
                                                            (float*)x1h, 64, 0, brg1, 0);

    // ---- layer 2: GAT(64 -> 4x32 concat): packed fp16 logits+accum; x2h fp16 (OUTH) ----
    k_alds1<<<NB32, 256, 0, stream>>>(x1h, U1p, aldsEh);
    k_gatx<64, 64><<<NB4, 256, 0, stream>>>(rp, srcs2, aldsEh, x1h, msg1h);
    k_mfma<64, 32, 0, 1><<<dim3(NTW, 4), 256, 0, stream>>>(msg1h, 256, 64, wg1rpk, 4096,
                                                           (float*)x2h, 128, 32, bg1, 32);

    // ---- layer 3: RGCN(128->32)+relu; L3 MFMA split 6-tiles x 3 y-slices ----
    k_mfmaL3<<<dim3(NTW, 3), 256, 0, stream>>>(x2h, Wcatpk, x3, ybuf3h);
    k_agg2<<<NB4, 256, 0, stream>>>(rp, srcs2, ybuf3h, brg2, U2p, x3, x3h, aldsEh);

    // ---- layer 4: GAT(32 -> 4x16, mean heads) + relu + tanh ----
    k_gatx<32, 32><<<NB4, 256, 0, stream>>>(rp, srcs2, aldsEh, x3h, msg2h);
    k_final<<<NB32, 256, 0, stream>>>(msg2h, Wstk, bg2, out);
}

// Round 17
// 379.370 us; speedup vs baseline: 1.0339x; 1.0059x over previous
//
#include <hip/hip_runtime.h>
#include <math.h>

#define NN 50000
#define EE 800000
#define RR 8
#define SLOPE 0.2f
#define SEGS (NN * RR)            /* 400000 per-(node,relation) segments */
#define NTW ((NN + 63) / 64)      /* 782 mfma row-tiles (64 rows each) */
#define NBUK 98                   /* coarse buckets: dst>>9 (512 dst values each) */
#define SEGB 4096                 /* segments per bucket = 512 * RR */
#define EB4 ((EE + 4095) / 4096)  /* 196 fillA/hist blocks */
#define XB ((NN * 8 + 255) / 256) /* 1563 xh blocks */

typedef __attribute__((ext_vector_type(4))) float f32x4;
typedef _Float16 f16;
typedef __attribute__((ext_vector_type(4))) _Float16 h4;
typedef __attribute__((ext_vector_type(8))) _Float16 h8;

__device__ __forceinline__ void fmacc(float4& a, const float4& v, float p) {
    a.x = fmaf(v.x, p, a.x);
    a.y = fmaf(v.y, p, a.y);
    a.z = fmaf(v.z, p, a.z);
    a.w = fmaf(v.w, p, a.w);
}

__device__ __forceinline__ void red4(float4& a, int m) {
    a.x += __shfl_xor(a.x, m);
    a.y += __shfl_xor(a.y, m);
    a.z += __shfl_xor(a.z, m);
    a.w += __shfl_xor(a.w, m);
}

__device__ __forceinline__ float4 h4tof4(h4 t) {
    return make_float4((float)t[0], (float)t[1], (float)t[2], (float)t[3]);
}

__device__ __forceinline__ h4 hmax4(h4 a, h4 b) {
    h4 r;
    r[0] = a[0] > b[0] ? a[0] : b[0];
    r[1] = a[1] > b[1] ? a[1] : b[1];
    r[2] = a[2] > b[2] ? a[2] : b[2];
    r[3] = a[3] > b[3] ? a[3] : b[3];
    return r;
}

__device__ __forceinline__ h4 hsplat(f16 s) { return (h4){s, s, s, s}; }

// ============================ CSR build (bucket-local) + fused fp16 x copy ============================
__global__ __launch_bounds__(256) void k_histxh(const int* __restrict__ dst,
                                                int* __restrict__ buccnt,
                                                const float* __restrict__ X,
                                                f16* __restrict__ xh) {
    __shared__ int h[NBUK];
    int b = blockIdx.x;
    int tid = threadIdx.x;
    if (b < EB4) {  // histogram part
        for (int i = tid; i < NBUK; i += 256) h[i] = 0;
        __syncthreads();
        int e0 = b * 4096;
        int cnt = EE - e0;
        if (cnt > 4096) cnt = 4096;
        for (int i = tid; i < cnt; i += 256) atomicAdd(&h[dst[e0 + i] >> 9], 1);
        __syncthreads();
        for (int i = tid; i < NBUK; i += 256)
            if (h[i]) atomicAdd(&buccnt[i], h[i]);
    } else {  // xh part
        int i = (b - EB4) * 256 + tid;
        if (i >= NN * 8) return;
        float4 v0 = *(const float4*)(X + (size_t)i * 8);
        float4 v1 = *(const float4*)(X + (size_t)i * 8 + 4);
        h8 hv = {(f16)v0.x, (f16)v0.y, (f16)v0.z, (f16)v0.w,
                 (f16)v1.x, (f16)v1.y, (f16)v1.z, (f16)v1.w};
        *(h8*)(xh + (size_t)i * 8) = hv;
    }
}

__global__ void k_scan98(const int* __restrict__ buccnt, int* __restrict__ bucbase,
                         int* __restrict__ cbcur) {
    __shared__ int sh[128];
    int t = threadIdx.x;
    int v = (t < NBUK) ? buccnt[t] : 0;
    sh[t] = v;
    __syncthreads();
    for (int off = 1; off < 128; off <<= 1) {
        int u = (t >= off) ? sh[t - off] : 0;
        __syncthreads();
        sh[t] += u;
        __syncthreads();
    }
    int excl = sh[t] - v;
    if (t <= NBUK) bucbase[t] = excl;  // bucbase[NBUK] == EE
    if (t < NBUK) cbcur[t] = excl;
}

// ===== fill phase A: bin edges into recbuf in coarse-bucket-major order =====
__global__ __launch_bounds__(256) void k_fillA(const int* __restrict__ src,
                                               const int* __restrict__ dst,
                                               const int* __restrict__ et,
                                               int* __restrict__ cbcur,
                                               int* __restrict__ recbuf) {
    __shared__ int hist[NBUK], lcur[NBUK], gres[NBUK];
    int tid = threadIdx.x;
    int e0 = blockIdx.x * 4096;
    int cnt = EE - e0;
    if (cnt > 4096) cnt = 4096;
    for (int i = tid; i < NBUK; i += 256) { hist[i] = 0; lcur[i] = 0; }
    __syncthreads();
    int myb[16], myrec[16];
#pragma unroll
    for (int j = 0; j < 16; j++) {
        int i = tid + j * 256;
        if (i < cnt) {
            int e = e0 + i;
            int d = dst[e];
            int b = d >> 9;
            myb[j] = b;
            myrec[j] = ((d & 511) << 19) | (src[e] << 3) | et[e];
            atomicAdd(&hist[b], 1);
        } else {
            myb[j] = -1;
            myrec[j] = 0;
        }
    }
    __syncthreads();
    if (tid < NBUK) gres[tid] = atomicAdd(&cbcur[tid], hist[tid]);
    __syncthreads();
#pragma unroll
    for (int j = 0; j < 16; j++) {
        if (myb[j] >= 0) {
            int p = atomicAdd(&lcur[myb[j]], 1);
            recbuf[gres[myb[j]] + p] = myrec[j];
        }
    }
}

// ===== fill phase B2: one block per bucket; counts+scan+rp-write+scatter in LDS =====
__global__ __launch_bounds__(256) void k_fillB2(const int* __restrict__ bucbase,
                                                const int* __restrict__ recbuf,
                                                int* __restrict__ rp,
                                                int* __restrict__ srcs2) {
    __shared__ int cnt[SEGB];
    __shared__ int psc[256];
    int b = blockIdx.x;
    int segbase = b * SEGB;
    int nseg = SEGS - segbase;
    if (nseg > SEGB) nseg = SEGB;
    int base = bucbase[b];
    int cntE = bucbase[b + 1] - base;
    int tid = threadIdx.x;
    for (int s = tid; s < SEGB; s += 256) cnt[s] = 0;
    __syncthreads();
    for (int i = tid; i < cntE; i += 256) {
        int rec = recbuf[base + i];
        int segl = ((rec >> 19) << 3) | (rec & 7);
        atomicAdd(&cnt[segl], 1);
    }
    __syncthreads();
    int loc[16];
    int sbase = tid * 16;
    int run = 0;
#pragma unroll
    for (int j = 0; j < 16; j++) { loc[j] = cnt[sbase + j]; run += loc[j]; }
    psc[tid] = run;
    __syncthreads();
    for (int off = 1; off < 256; off <<= 1) {
        int u = (tid >= off) ? psc[tid - off] : 0;
        __syncthreads();
        psc[tid] += u;
        __syncthreads();
    }
    int excl = psc[tid] - run;
#pragma unroll
    for (int j = 0; j < 16; j++) {
        int s = sbase + j;
        int v = loc[j];
        cnt[s] = excl;
        if (s < nseg) rp[segbase + s] = base + excl;
        excl += v;
    }
    __syncthreads();
    for (int i = tid; i < cntE; i += 256) {
        int rec = recbuf[base + i];
        int segl = ((rec >> 19) << 3) | (rec & 7);
        int p = atomicAdd(&cnt[segl], 1);
        srcs2[base + p] = rec & 0x7FFFF;
    }
    if (b == NBUK - 1 && tid == 0) rp[SEGS] = EE;
}

// ==== prep (merged): padded weights, logit projections, stacked Wb1, Wcat2e compose ====
__global__ void k_prep(const float* __restrict__ wg1, const float* __restrict__ wg2,
                       const float* __restrict__ root1, const float* __restrict__ root2,
                       const float* __restrict__ basis1, const float* __restrict__ basis2,
                       const float* __restrict__ comp2,
                       const float* __restrict__ asrc1, const float* __restrict__ adst1,
                       const float* __restrict__ asrc2, const float* __restrict__ adst2,
                       float* __restrict__ Wcat2e, float* __restrict__ wg1r,
                       float* __restrict__ Wstk, float* __restrict__ U1p,
                       float* __restrict__ U2p, float* __restrict__ Wb1) {
    int idx = blockIdx.x * 256 + threadIdx.x;
    if (idx < 16384) {  // wg1r[h][k][c] (c<32 valid)
        int h = idx >> 12, kc = idx & 4095;
        int k = kc >> 6, c = kc & 63;
        wg1r[idx] = (c < 32) ? wg1[k * 128 + h * 32 + c] : 0.f;
    } else if (idx < 24576) {  // Wstk[h*32+k][c] = wg2[k][h*16+c] (c<16 valid)
        int j = idx - 16384;
        int row = j >> 6, c = j & 63;
        int h = row >> 5, k = row & 31;
        Wstk[j] = (c < 16) ? wg2[k * 64 + h * 16 + c] : 0.f;
    } else if (idx < 32768) {  // Wcat2e root block: [128][col 0-63] = root2 zero-padded
        int j = idx - 24576;
        int k = j >> 6, c = j & 63;
        Wcat2e[k * 320 + c] = (c < 32) ? root2[k * 32 + c] : 0.f;
    } else if (idx < 36864) {  // U1p[k][j]
        int j0 = idx - 32768;
        int k = j0 >> 6, j = j0 & 63;
        float s = 0.f;
        if (j < 8) {
            int h = j & 3;
            const float* a = (j < 4) ? asrc1 : adst1;
            for (int c = 0; c < 32; c++) s += wg1[k * 128 + h * 32 + c] * a[h * 32 + c];
        }
        U1p[j0] = s;
    } else if (idx < 38912) {  // U2p[k][j]
        int j0 = idx - 36864;
        int k = j0 >> 6, j = j0 & 63;
        float s = 0.f;
        if (j < 8) {
            int h = j & 3;
            const float* a = (j < 4) ? asrc2 : adst2;
            for (int c = 0; c < 16; c++) s += wg2[k * 64 + h * 16 + c] * a[h * 16 + c];
        }
        U2p[j0] = s;
    } else if (idx < 55296) {  // Wb1 rows 0-255 = basis1 flat copy
        Wb1[idx - 38912] = basis1[idx - 38912];
    } else if (idx < 59392) {  // Wb1 rows 256-319 = root1
        Wb1[idx - 38912] = root1[idx - 55296];
    } else if (idx < 92160) {  // Wcat2e basis-composed block: [128][col 64-319]
        int j = idx - 59392;
        int i = j >> 8, rc = j & 255;
        int r = rc >> 5, o = rc & 31;
        float acc = 0.f;
#pragma unroll
        for (int b = 0; b < 4; b++) acc += comp2[r * 4 + b] * basis2[b * 4096 + i * 32 + o];
        Wcat2e[i * 320 + 64 + rc] = acc;
    }
}

// ==== pack weights into fp16 hi/lo MFMA fragment order (A is fp16 -> native f16 MFMA) ====
__global__ void k_pack(const float* __restrict__ Wb1, const float* __restrict__ wg1r,
                       const float* __restrict__ Wcat, short* __restrict__ pWb1,
                       short* __restrict__ pwg1r, short* __restrict__ pWcat) {
    int u = blockIdx.x * 256 + threadIdx.x;
    int lane = u & 63, pair = u >> 6;
    if (pair >= 136) return;
    int m = lane & 15, g = lane >> 4;
    const float* src;
    int ldB, col, k0;
    short* dst;
    if (pair < 40) {
        int ct = pair / 10, kc = pair % 10;
        src = Wb1; ldB = 64; col = ct * 16 + m; k0 = kc * 32 + g * 8;
        dst = pWb1 + pair * 1024 + lane * 8;
    } else if (pair < 56) {
        int q = pair - 40;
        int h = q >> 2, lp = q & 3, ct = lp >> 1, kc = lp & 1;
        src = wg1r + h * 4096; ldB = 64; col = ct * 16 + m; k0 = kc * 32 + g * 8;
        dst = pwg1r + q * 1024 + lane * 8;
    } else {
        int q = pair - 56;
        int p = q >> 4, lp = q & 15, ct = lp >> 2, kc = lp & 3;
        src = Wcat; ldB = 320; col = p * 64 + ct * 16 + m; k0 = kc * 32 + g * 8;
        dst = pWcat + q * 1024 + lane * 8;
    }
    h8 H, L;
#pragma unroll
    for (int r = 0; r < 8; r++) {
        float e = src[(size_t)(k0 + r) * ldB + col];
        f16 hi = (f16)e;
        H[r] = hi;
        L[r] = (f16)(e - (float)hi);
    }
    *(h8*)dst = H;
    *(h8*)(dst + 512) = L;
}

// ============ MFMA GEMM (fp16 A, fp16 hi/lo B, 2-term): 4 waves x 16 rows, NCOL cols ============
template <int KTOT, int NCOL, int ACT = 0, int OUTH = 0>
__global__ __launch_bounds__(256) void k_mfma(const f16* __restrict__ X, int ldX, int xmb,
                                              const short* __restrict__ Bpk, int bmb,
                                              float* __restrict__ Y, int ldY, size_t ymb,
                                              const float* __restrict__ bias, int biasmb) {
    constexpr int NKC = KTOT / 32;
    constexpr int NCT = NCOL / 16;
    const int tid = threadIdx.x;
    const int wid = tid >> 6, lane = tid & 63;
    const int m = lane & 15, g = lane >> 4;
    const int mb = blockIdx.y;
    const int rowbase = blockIdx.x * 64 + wid * 16;
    if (rowbase >= NN) return;  // NN % 16 == 0: per-wave all-or-nothing
    const f16* Xm = X + (size_t)mb * xmb + (size_t)(rowbase + m) * ldX;
    const short* Bm = Bpk + (size_t)mb * bmb;

    f32x4 acc[NCT];
#pragma unroll
    for (int c = 0; c < NCT; c++) acc[c] = (f32x4){0.f, 0.f, 0.f, 0.f};

#pragma unroll
    for (int kc = 0; kc < NKC; kc++) {
        h8 av = *(const h8*)(Xm + kc * 32 + g * 8);
#pragma unroll
        for (int ct = 0; ct < NCT; ct++) {
            const short* bp = Bm + (size_t)(ct * NKC + kc) * 1024 + lane * 8;
            h8 bh = *(const h8*)bp;
            h8 bl = *(const h8*)(bp + 512);
            acc[ct] = __builtin_amdgcn_mfma_f32_16x16x32_f16(av, bh, acc[ct], 0, 0, 0);
            acc[ct] = __builtin_amdgcn_mfma_f32_16x16x32_f16(av, bl, acc[ct], 0, 0, 0);
        }
    }

#pragma unroll
    for (int ct = 0; ct < NCT; ct++) {
        int col = ct * 16 + m;
        float bv = bias ? bias[mb * biasmb + col] : 0.f;
#pragma unroll
        for (int i = 0; i < 4; i++) {
            float o = acc[ct][i] + bv;
            if (ACT == 2) o = fmaxf(o, 0.f);
            if (OUTH) {
                f16* Yh = (f16*)Y;
                Yh[(size_t)mb * ymb + (size_t)(rowbase + g * 4 + i) * ldY + col] = (f16)o;
            } else {
                Y[(size_t)mb * ymb + (size_t)(rowbase + g * 4 + i) * ldY + col] = o;
            }
        }
    }
}

// ===== L3 transform: 18 live col-tiles split 6-per-blockIdx.y (fp16 2-term MFMA) =====
__global__ __launch_bounds__(256) void k_mfmaL3(const f16* __restrict__ Xh,
                                                const short* __restrict__ Bpk,
                                                float* __restrict__ x3,
                                                f16* __restrict__ ybuf3h) {
    const int tid = threadIdx.x;
    const int wid = tid >> 6, lane = tid & 63;
    const int m = lane & 15, g = lane >> 4;
    const int y = blockIdx.y;
    const int rowbase = blockIdx.x * 64 + wid * 16;
    if (rowbase >= NN) return;
    const f16* Xm = Xh + (size_t)(rowbase + m) * 128;

    f32x4 acc[6];
#pragma unroll
    for (int j = 0; j < 6; j++) acc[j] = (f32x4){0.f, 0.f, 0.f, 0.f};

#pragma unroll
    for (int kc = 0; kc < 4; kc++) {
        h8 av = *(const h8*)(Xm + kc * 32 + g * 8);
#pragma unroll
        for (int j = 0; j < 6; j++) {
            int bct = (y == 0) ? ((j < 2) ? j : j + 2) : (8 + (y - 1) * 6 + j);
            const short* bp = Bpk + (size_t)(bct * 4 + kc) * 1024 + lane * 8;
            h8 bh = *(const h8*)bp;
            h8 bl = *(const h8*)(bp + 512);
            acc[j] = __builtin_amdgcn_mfma_f32_16x16x32_f16(av, bh, acc[j], 0, 0, 0);
            acc[j] = __builtin_amdgcn_mfma_f32_16x16x32_f16(av, bl, acc[j], 0, 0, 0);
        }
    }
#pragma unroll
    for (int j = 0; j < 6; j++) {
        int bct = (y == 0) ? ((j < 2) ? j : j + 2) : (8 + (y - 1) * 6 + j);
        if (bct < 2) {  // root cols 0-31 -> x3 fp32 compact [n][32]
            int col = bct * 16 + m;
#pragma unroll
            for (int r = 0; r < 4; r++) {
                int n = rowbase + g * 4 + r;
                x3[(size_t)n * 32 + col] = acc[j][r];
            }
        } else {  // rel col gcol = bct*16+m-64 -> panel p, col cc (fp16)
            int gcol = bct * 16 + m - 64;
            int p = gcol >> 6, cc = gcol & 63;
            f16* Yp = ybuf3h + (size_t)p * NN * 64;
#pragma unroll
            for (int r = 0; r < 4; r++) {
                int n = rowbase + g * 4 + r;
                Yp[(size_t)n * 64 + cc] = (f16)acc[j][r];
            }
        }
    }
}

// ===== L1 basis-space gather: packed-fp16 accumulation, 4-edge ILP; U[n][b][64]; U[n][4][64]=x[n] =====
__global__ __launch_bounds__(256) void k_gagg1(const int* __restrict__ rp,
                                               const int* __restrict__ srcs2,
                                               const float* __restrict__ comp,
                                               const f16* __restrict__ Xh,
                                               f16* __restrict__ Uh) {
    __shared__ h4 sh_w[4][8];
    int wid = threadIdx.x >> 6, lane = threadIdx.x & 63;
    int n = blockIdx.x * 4 + wid;
    int rpv = (lane <= 8) ? rp[n * RR + lane] : 0;
    int nxt = __shfl(rpv, (lane + 1) & 63);
    if (lane < 8) {
        float inv = 1.f / (float)((nxt - rpv) > 0 ? (nxt - rpv) : 1);
        float4 c = *(const float4*)(comp + lane * 4);
        sh_w[wid][lane] = (h4){(f16)(c.x * inv), (f16)(c.y * inv),
                               (f16)(c.z * inv), (f16)(c.w * inv)};
    }
    int q = lane & 15;
    int beg = rp[n * RR], end = rp[n * RR + RR];
    h4 hz = {(f16)0.f, (f16)0.f, (f16)0.f, (f16)0.f};
    h4 a0 = hz, a1 = hz, a2 = hz, a3 = hz;
    int k = beg + (lane >> 4);
    for (; k + 12 < end; k += 16) {  // 4 edges in flight per row-group
        int key0 = srcs2[k], key1 = srcs2[k + 4];
        int key2 = srcs2[k + 8], key3 = srcs2[k + 12];
        h4 w0 = sh_w[wid][key0 & 7], w1 = sh_w[wid][key1 & 7];
        h4 w2 = sh_w[wid][key2 & 7], w3 = sh_w[wid][key3 & 7];
        h4 v0 = *(const h4*)(Xh + (size_t)(key0 >> 3) * 64 + q * 4);
        h4 v1 = *(const h4*)(Xh + (size_t)(key1 >> 3) * 64 + q * 4);
        h4 v2 = *(const h4*)(Xh + (size_t)(key2 >> 3) * 64 + q * 4);
        h4 v3 = *(const h4*)(Xh + (size_t)(key3 >> 3) * 64 + q * 4);
        a0 += hsplat(w0[0]) * v0;
        a1 += hsplat(w0[1]) * v0;
        a2 += hsplat(w0[2]) * v0;
        a3 += hsplat(w0[3]) * v0;
        a0 += hsplat(w1[0]) * v1;
        a1 += hsplat(w1[1]) * v1;
        a2 += hsplat(w1[2]) * v1;
        a3 += hsplat(w1[3]) * v1;
        a0 += hsplat(w2[0]) * v2;
        a1 += hsplat(w2[1]) * v2;
        a2 += hsplat(w2[2]) * v2;
        a3 += hsplat(w2[3]) * v2;
        a0 += hsplat(w3[0]) * v3;
        a1 += hsplat(w3[1]) * v3;
        a2 += hsplat(w3[2]) * v3;
        a3 += hsplat(w3[3]) * v3;
    }
    for (; k < end; k += 4) {
        int key0 = srcs2[k];
        h4 w0 = sh_w[wid][key0 & 7];
        h4 v0 = *(const h4*)(Xh + (size_t)(key0 >> 3) * 64 + q * 4);
        a0 += hsplat(w0[0]) * v0;
        a1 += hsplat(w0[1]) * v0;
        a2 += hsplat(w0[2]) * v0;
        a3 += hsplat(w0[3]) * v0;
    }
    float4 A0 = h4tof4(a0), A1 = h4tof4(a1), A2 = h4tof4(a2), A3 = h4tof4(a3);
    red4(A0, 16); red4(A0, 32);
    red4(A1, 16); red4(A1, 32);
    red4(A2, 16); red4(A2, 32);
    red4(A3, 16); red4(A3, 32);
    if (lane < 16) {
        f16* un = Uh + (size_t)n * 320;
        h4 o0 = {(f16)A0.x, (f16)A0.y, (f16)A0.z, (f16)A0.w};
        h4 o1 = {(f16)A1.x, (f16)A1.y, (f16)A1.z, (f16)A1.w};
        h4 o2 = {(f16)A2.x, (f16)A2.y, (f16)A2.z, (f16)A2.w};
        h4 o3 = {(f16)A3.x, (f16)A3.y, (f16)A3.z, (f16)A3.w};
        *(h4*)(un + 0 * 64 + q * 4) = o0;
        *(h4*)(un + 1 * 64 + q * 4) = o1;
        *(h4*)(un + 2 * 64 + q * 4) = o2;
        *(h4*)(un + 3 * 64 + q * 4) = o3;
        *(h4*)(un + 256 + q * 4) = *(const h4*)(Xh + (size_t)n * 64 + q * 4);
    }
}

// ===== skinny matvec on fp16 x1h + fp16 exp-logit emit =====
__global__ __launch_bounds__(256) void k_alds1(const f16* __restrict__ X1h,
                                               const float* __restrict__ U1p,
                                               f16* __restrict__ aldsEh) {
    __shared__ float sUT[8 * 68];
    int tid = threadIdx.x;
    for (int i = tid; i < 512; i += 256) {
        int j = i >> 6, c = i & 63;
        sUT[j * 68 + c] = U1p[c * 64 + j];
    }
    __syncthreads();
    int lane = tid & 63, wid = tid >> 6;
    int n = blockIdx.x * 32 + wid * 8 + (lane >> 3);
    int q = lane & 7;
    float x[8];
    if (n < NN) {
        h8 hv = *(const h8*)(X1h + (size_t)n * 64 + q * 8);
#pragma unroll
        for (int c = 0; c < 8; c++) x[c] = (float)hv[c];
    } else {
#pragma unroll
        for (int c = 0; c < 8; c++) x[c] = 0.f;
    }
    float al[8];
#pragma unroll
    for (int j = 0; j < 8; j++) {
        const float* u = &sUT[j * 68 + q * 8];
        float s = 0.f;
#pragma unroll
        for (int c = 0; c < 8; c++) s += x[c] * u[c];
        al[j] = s;
    }
#pragma unroll
    for (int m = 1; m < 8; m <<= 1)
#pragma unroll
        for (int j = 0; j < 8; j++) al[j] += __shfl_xor(al[j], m);
    if (n < NN) {
        float av = al[q];
        int pos = (q < 4) ? q : q + 4;  // Es 0-3, Es2 4-7, Ed 8-11, Ed2 12-15
        aldsEh[(size_t)n * 16 + pos] = (f16)__expf(av);
        aldsEh[(size_t)n * 16 + pos + 4] = (f16)__expf(SLOPE * av);
    }
}

// ===== skinny final: msg2 fp16 input =====
__global__ __launch_bounds__(256) void k_final(const f16* __restrict__ Xm,
                                               const float* __restrict__ Wstk,
                                               const float* __restrict__ bg2,
                                               float* __restrict__ out) {
    __shared__ float sWT[16 * 132];
    int tid = threadIdx.x;
    for (int i = tid; i < 2048; i += 256) {
        int c = i >> 7, k = i & 127;
        sWT[c * 132 + k] = Wstk[k * 64 + c];
    }
    __syncthreads();
    int lane = tid & 63, wid = tid >> 6;
    int n = blockIdx.x * 32 + wid * 8 + (lane >> 3);
    int q = lane & 7;
    float x[16];
    if (n < NN) {
#pragma unroll
        for (int t = 0; t < 4; t++) {
            float4 v = h4tof4(*(const h4*)(Xm + (size_t)n * 128 + t * 32 + q * 4));
            x[t * 4 + 0] = v.x; x[t * 4 + 1] = v.y; x[t * 4 + 2] = v.z; x[t * 4 + 3] = v.w;
        }
    } else {
#pragma unroll
        for (int k = 0; k < 16; k++) x[k] = 0.f;
    }
    float al[16];
#pragma unroll
    for (int c = 0; c < 16; c++) {
        float s = 0.f;
#pragma unroll
        for (int t = 0; t < 4; t++) {
            const float* w = &sWT[c * 132 + t * 32 + q * 4];
            s += x[t * 4 + 0] * w[0] + x[t * 4 + 1] * w[1] + x[t * 4 + 2] * w[2] +
                 x[t * 4 + 3] * w[3];
        }
        al[c] = s;
    }
#pragma unroll
    for (int m = 1; m < 8; m <<= 1)
#pragma unroll
        for (int c = 0; c < 16; c++) al[c] += __shfl_xor(al[c], m);
    if (n < NN && q < 4) {
        float4 bv = *(const float4*)(bg2 + q * 4);
        float4 v;
        v.x = tanhf(fmaxf(0.25f * al[q * 4 + 0] + bv.x, 0.f));
        v.y = tanhf(fmaxf(0.25f * al[q * 4 + 1] + bv.y, 0.f));
        v.z = tanhf(fmaxf(0.25f * al[q * 4 + 2] + bv.z, 0.f));
        v.w = tanhf(fmaxf(0.25f * al[q * 4 + 3] + bv.w, 0.f));
        *(float4*)(out + (size_t)n * 16 + q * 4) = v;
    }
}

// ===== aggregate 2 + fused fp16 exp-logit emit (x3prev compact [n][32] fp32), 4-edge ILP =====
__global__ __launch_bounds__(256) void k_agg2(const int* __restrict__ rp,
                                              const int* __restrict__ srcs2,
                                              const f16* __restrict__ y,
                                              const float* __restrict__ bias,
                                              const float* __restrict__ U2p,
                                              const float* __restrict__ x3prev,
                                              f16* __restrict__ x3h,
                                              f16* __restrict__ aldsEh) {
    __shared__ float sh_inv[4][8];
    int wid = threadIdx.x >> 6, lane = threadIdx.x & 63;
    int n = blockIdx.x * 4 + wid;
    int rpv = (lane <= 8) ? rp[n * RR + lane] : 0;
    int nxt = __shfl(rpv, (lane + 1) & 63);
    if (lane < 8) sh_inv[wid][lane] = 1.f / (float)((nxt - rpv) > 0 ? (nxt - rpv) : 1);
    int q = lane & 7;
    int beg = rp[n * RR], end = rp[n * RR + RR];
    float4 acc = make_float4(0.f, 0.f, 0.f, 0.f);
    int k = beg + (lane >> 3);
    for (; k + 24 < end; k += 32) {  // 4 edges in flight per group
        int key0 = srcs2[k], key1 = srcs2[k + 8];
        int key2 = srcs2[k + 16], key3 = srcs2[k + 24];
        int s0 = key0 >> 3, s1 = key1 >> 3, s2 = key2 >> 3, s3 = key3 >> 3;
        int g0 = key0 & 7, g1 = key1 & 7, g2 = key2 & 7, g3 = key3 & 7;
        float4 v0 = h4tof4(*(const h4*)(y + ((size_t)(g0 >> 1) * NN + s0) * 64 + (g0 & 1) * 32 + q * 4));
        float4 v1 = h4tof4(*(const h4*)(y + ((size_t)(g1 >> 1) * NN + s1) * 64 + (g1 & 1) * 32 + q * 4));
        float4 v2 = h4tof4(*(const h4*)(y + ((size_t)(g2 >> 1) * NN + s2) * 64 + (g2 & 1) * 32 + q * 4));
        float4 v3 = h4tof4(*(const h4*)(y + ((size_t)(g3 >> 1) * NN + s3) * 64 + (g3 & 1) * 32 + q * 4));
        fmacc(acc, v0, sh_inv[wid][g0]);
        fmacc(acc, v1, sh_inv[wid][g1]);
        fmacc(acc, v2, sh_inv[wid][g2]);
        fmacc(acc, v3, sh_inv[wid][g3]);
    }
    for (; k < end; k += 8) {
        int key0 = srcs2[k];
        int s0 = key0 >> 3;
        int g0 = key0 & 7;
        float4 v0 = h4tof4(*(const h4*)(y + ((size_t)(g0 >> 1) * NN + s0) * 64 + (g0 & 1) * 32 + q * 4));
        fmacc(acc, v0, sh_inv[wid][g0]);
    }
    red4(acc, 8);
    red4(acc, 16);
    red4(acc, 32);
    if (lane < 8) {
        float4 prev = *(const float4*)(x3prev + (size_t)n * 32 + q * 4);
        float4 b = *(const float4*)(bias + q * 4);
        float4 v;
        v.x = fmaxf(prev.x + acc.x + b.x, 0.f);
        v.y = fmaxf(prev.y + acc.y + b.y, 0.f);
        v.z = fmaxf(prev.z + acc.z + b.z, 0.f);
        v.w = fmaxf(prev.w + acc.w + b.w, 0.f);
        h4 hv = {(f16)v.x, (f16)v.y, (f16)v.z, (f16)v.w};
        *(h4*)(x3h + (size_t)n * 32 + q * 4) = hv;
        float al[8];
#pragma unroll
        for (int j = 0; j < 8; j++) {
            al[j] = fmaf(v.x, U2p[(q * 4 + 0) * 64 + j],
                    fmaf(v.y, U2p[(q * 4 + 1) * 64 + j],
                    fmaf(v.z, U2p[(q * 4 + 2) * 64 + j],
                         v.w * U2p[(q * 4 + 3) * 64 + j])));
        }
#pragma unroll
        for (int m = 1; m < 8; m <<= 1) {
#pragma unroll
            for (int j = 0; j < 8; j++) al[j] += __shfl_xor(al[j], m);
        }
        float av = al[q];
        int pos = (q < 4) ? q : q + 4;
        aldsEh[(size_t)n * 16 + pos] = (f16)__expf(av);
        aldsEh[(size_t)n * 16 + pos + 4] = (f16)__expf(SLOPE * av);
    }
}

// ===== fused GAT aggregation: packed-fp16 logits AND accumulation, 4-edge ILP =====
// acc/z in fp16 (bounded: logits ~ +/-0.5 -> p in [0.6,1.7], z <= ~30, msg sums O(10)).
template <int F, int LDX = F>
__global__ __launch_bounds__(256) void k_gatx(const int* __restrict__ rp,
                                              const int* __restrict__ srcs2,
                                              const f16* __restrict__ aldsEh,
                                              const f16* __restrict__ X,
                                              f16* __restrict__ msg) {
    constexpr int G = F / 4;    // lanes per edge-group (16 or 8)
    constexpr int NG = 64 / G;  // groups per wave (4 or 8)
    int wid = threadIdx.x >> 6, lane = threadIdx.x & 63;
    int n = blockIdx.x * 4 + wid;
    if (n >= NN) return;
    int g = lane / G, q = lane % G;
    h4 EdH = *(const h4*)(aldsEh + (size_t)n * 16 + 8);
    h4 Ed2H = *(const h4*)(aldsEh + (size_t)n * 16 + 12);
    h4 hz = {(f16)0.f, (f16)0.f, (f16)0.f, (f16)0.f};
    h4 acc0 = hz, acc1 = hz, acc2 = hz, acc3 = hz, zH = hz;
    if (g == 0) {  // self loop
        h4 es = *(const h4*)(aldsEh + (size_t)n * 16);
        h4 es2 = *(const h4*)(aldsEh + (size_t)n * 16 + 4);
        h4 xv = *(const h4*)(X + (size_t)n * LDX + q * 4);
        h4 pH = hmax4(es * EdH, es2 * Ed2H);
        zH += pH;
        acc0 += hsplat(pH[0]) * xv;
        acc1 += hsplat(pH[1]) * xv;
        acc2 += hsplat(pH[2]) * xv;
        acc3 += hsplat(pH[3]) * xv;
    }
    int beg = rp[n * RR], end = rp[n * RR + RR];
    int k = beg + g;
    for (; k + 3 * NG < end; k += 4 * NG) {  // 4 edges in flight per group
        int s0 = srcs2[k] >> 3, s1 = srcs2[k + NG] >> 3;
        int s2 = srcs2[k + 2 * NG] >> 3, s3 = srcs2[k + 3 * NG] >> 3;
        h8 e0 = *(const h8*)(aldsEh + (size_t)s0 * 16);
        h8 e1 = *(const h8*)(aldsEh + (size_t)s1 * 16);
        h8 e2 = *(const h8*)(aldsEh + (size_t)s2 * 16);
        h8 e3 = *(const h8*)(aldsEh + (size_t)s3 * 16);
        h4 x0 = *(const h4*)(X + (size_t)s0 * LDX + q * 4);
        h4 x1v = *(const h4*)(X + (size_t)s1 * LDX + q * 4);
        h4 x2v = *(const h4*)(X + (size_t)s2 * LDX + q * 4);
        h4 x3v = *(const h4*)(X + (size_t)s3 * LDX + q * 4);
        h4 e0lo = {e0[0], e0[1], e0[2], e0[3]};
        h4 e0hi = {e0[4], e0[5], e0[6], e0[7]};
        h4 e1lo = {e1[0], e1[1], e1[2], e1[3]};
        h4 e1hi = {e1[4], e1[5], e1[6], e1[7]};
        h4 e2lo = {e2[0], e2[1], e2[2], e2[3]};
        h4 e2hi = {e2[4], e2[5], e2[6], e2[7]};
        h4 e3lo = {e3[0], e3[1], e3[2], e3[3]};
        h4 e3hi = {e3[4], e3[5], e3[6], e3[7]};
        h4 p0H = hmax4(e0lo * EdH, e0hi * Ed2H);
        h4 p1H = hmax4(e1lo * EdH, e1hi * Ed2H);
        h4 p2H = hmax4(e2lo * EdH, e2hi * Ed2H);
        h4 p3H = hmax4(e3lo * EdH, e3hi * Ed2H);
        zH += p0H + p1H + p2H + p3H;
        acc0 += hsplat(p0H[0]) * x0;
        acc1 += hsplat(p0H[1]) * x0;
        acc2 += hsplat(p0H[2]) * x0;
        acc3 += hsplat(p0H[3]) * x0;
        acc0 += hsplat(p1H[0]) * x1v;
        acc1 += hsplat(p1H[1]) * x1v;
        acc2 += hsplat(p1H[2]) * x1v;
        acc3 += hsplat(p1H[3]) * x1v;
        acc0 += hsplat(p2H[0]) * x2v;
        acc1 += hsplat(p2H[1]) * x2v;
        acc2 += hsplat(p2H[2]) * x2v;
        acc3 += hsplat(p2H[3]) * x2v;
        acc0 += hsplat(p3H[0]) * x3v;
        acc1 += hsplat(p3H[1]) * x3v;
        acc2 += hsplat(p3H[2]) * x3v;
        acc3 += hsplat(p3H[3]) * x3v;
    }
    for (; k < end; k += NG) {
        int s0 = srcs2[k] >> 3;
        h8 e0 = *(const h8*)(aldsEh + (size_t)s0 * 16);
        h4 x0 = *(const h4*)(X + (size_t)s0 * LDX + q * 4);
        h4 e0lo = {e0[0], e0[1], e0[2], e0[3]};
        h4 e0hi = {e0[4], e0[5], e0[6], e0[7]};
        h4 p0H = hmax4(e0lo * EdH, e0hi * Ed2H);
        zH += p0H;
        acc0 += hsplat(p0H[0]) * x0;
        acc1 += hsplat(p0H[1]) * x0;
        acc2 += hsplat(p0H[2]) * x0;
        acc3 += hsplat(p0H[3]) * x0;
    }
    float4 A0 = h4tof4(acc0), A1 = h4tof4(acc1), A2 = h4tof4(acc2), A3 = h4tof4(acc3);
    float4 z = h4tof4(zH);
#pragma unroll
    for (int m = G; m < 64; m <<= 1) {
        red4(A0, m);
        red4(A1, m);
        red4(A2, m);
        red4(A3, m);
        red4(z, m);
    }
    if (g == 0) {
        float4 iz = make_float4(1.f / z.x, 1.f / z.y, 1.f / z.z, 1.f / z.w);
        f16* mp = msg + (size_t)n * 4 * F + q * 4;
        h4 o0 = {(f16)(A0.x * iz.x), (f16)(A0.y * iz.x), (f16)(A0.z * iz.x), (f16)(A0.w * iz.x)};
        h4 o1 = {(f16)(A1.x * iz.y), (f16)(A1.y * iz.y), (f16)(A1.z * iz.y), (f16)(A1.w * iz.y)};
        h4 o2 = {(f16)(A2.x * iz.z), (f16)(A2.y * iz.z), (f16)(A2.z * iz.z), (f16)(A2.w * iz.z)};
        h4 o3 = {(f16)(A3.x * iz.w), (f16)(A3.y * iz.w), (f16)(A3.z * iz.w), (f16)(A3.w * iz.w)};
        *(h4*)(mp + 0 * F) = o0;
        *(h4*)(mp + 1 * F) = o1;
        *(h4*)(mp + 2 * F) = o2;
        *(h4*)(mp + 3 * F) = o3;
    }
}

extern "C" void kernel_launch(void* const* d_in, const int* in_sizes, int n_in,
                              void* d_out, int out_size, void* d_ws, size_t ws_size,
                              hipStream_t stream) {
    const float* x      = (const float*)d_in[0];
    const int*   ei     = (const int*)d_in[1];
    const int*   et     = (const int*)d_in[2];
    const float* basis1 = (const float*)d_in[3];
    const float* comp1  = (const float*)d_in[4];
    const float* root1  = (const float*)d_in[5];
    const float* brg1   = (const float*)d_in[6];
    const float* wg1    = (const float*)d_in[7];
    const float* asrc1  = (const float*)d_in[8];
    const float* adst1  = (const float*)d_in[9];
    const float* bg1    = (const float*)d_in[10];
    const float* basis2 = (const float*)d_in[11];
    const float* comp2  = (const float*)d_in[12];
    const float* root2  = (const float*)d_in[13];
    const float* brg2   = (const float*)d_in[14];
    const float* wg2    = (const float*)d_in[15];
    const float* asrc2  = (const float*)d_in[16];
    const float* adst2  = (const float*)d_in[17];
    const float* bg2    = (const float*)d_in[18];
    const int* src = ei;
    const int* dst = ei + EE;
    float* out = (float*)d_out;

    // ---- int region ----
    int* wsi = (int*)d_ws;
    size_t ioff = 0;
    auto ialloc = [&](size_t n) { int* p = wsi + ioff; ioff += (n + 3) & ~(size_t)3; return p; };
    int* rp   = ialloc(SEGS + 1);
    int* srcs2 = ialloc(EE);
    int* recbuf = ialloc(EE);
    int* cbcur = ialloc(128);
    int* buccnt = ialloc(128);
    int* bucbase = ialloc(128);
    // ---- float region ----
    float* wsf = (float*)(wsi + ioff);
    size_t total_f = (ws_size - ioff * sizeof(int)) / sizeof(float);
    size_t P_f = (size_t)NN * 320;
    size_t need_f = P_f + (size_t)NN * 128
                  + 40960 + 20480 + 16384 + 8192 + 4096 + 2048
                  + (size_t)NN * 8
                  + 20480 + 8192 + 40960
                  + (size_t)NN * 32 + (size_t)NN * 16 + (size_t)NN * 32 + 64;
    if (total_f < need_f) return;  // loud fail: output stays zero
    size_t foff = 0;
    auto falloc = [&](size_t n) { float* p = wsf + foff; foff += (n + 3) & ~(size_t)3; return p; };
    float* P      = falloc(P_f);
    float* x2     = falloc((size_t)NN * 128);
    float* Wcat2e = falloc(40960);
    float* Wb1    = falloc(20480);
    float* wg1r   = falloc(16384);
    float* Wstk   = falloc(8192);
    float* U1p    = falloc(4096);
    float* U2p    = falloc(2048);
    f16* aldsEh   = (f16*)falloc((size_t)NN * 8);   // [n][16] f16: Es/Es2/Ed/Ed2
    short* Wb1pk  = (short*)falloc(20480);
    short* wg1rpk = (short*)falloc(8192);
    short* Wcatpk = (short*)falloc(40960);
    f16* x1h      = (f16*)falloc((size_t)NN * 32);  // [n][64] fp16 (u-gemm OUTH target)
    f16* x3h      = (f16*)falloc((size_t)NN * 16);  // [n][32] fp16
    f16* xh       = (f16*)falloc((size_t)NN * 32);  // [n][64] fp16 input copy
    f16* Uh = (f16*)P;                   // L1 basis-gather output [n][320] fp16
    f16* x2h = (f16*)x2;                 // [n][128] fp16 (msg1-gemm OUTH target)
    f16* msg1h  = (f16*)P;               // [n][4][64] fp16 (Uh dead after u-gemm)
    float* x3   = P;                     // fp32 root-panel out [n][32] compact
    f16* ybuf3h = (f16*)(P + (size_t)NN * 64);  // L3 rel panels [4][n][64] fp16
    f16* msg2h  = (f16*)(P + (size_t)NN * 64);  // [n][4][32] fp16 (ybuf3h dead after agg2)

    const int NB4 = (NN + 3) / 4;
    const int NB32 = (NN + 31) / 32;

    // ---- CSR build: fused hist+xh -> 98-scan -> binned fillA -> bucket-local fillB2 ----
    hipMemsetAsync(buccnt, 0, 128 * sizeof(int), stream);
    k_histxh<<<EB4 + XB, 256, 0, stream>>>(dst, buccnt, x, xh);
    k_scan98<<<1, 128, 0, stream>>>(buccnt, bucbase, cbcur);
    k_fillA<<<EB4, 256, 0, stream>>>(src, dst, et, cbcur, recbuf);
    k_fillB2<<<NBUK, 256, 0, stream>>>(bucbase, recbuf, rp, srcs2);
    k_prep<<<(92160 + 255) / 256, 256, 0, stream>>>(
        wg1, wg2, root1, root2, basis1, basis2, comp2, asrc1, adst1, asrc2, adst2,
        Wcat2e, wg1r, Wstk, U1p, U2p, Wb1);
    k_pack<<<34, 256, 0, stream>>>(Wb1, wg1r, Wcat2e, Wb1pk, wg1rpk, Wcatpk);

    // ---- layer 1: RGCN(64->64)+relu -> x1h fp16 directly (OUTH) ----
    k_gagg1<<<NB4, 256, 0, stream>>>(rp, srcs2, comp1, xh, Uh);
    k_mfma<320, 64, 2, 1><<<dim3(NTW, 1), 256, 0, stream>>>(Uh, 320, 0, Wb1pk, 0,
                                                            (float*)x1h, 64, 0, brg1, 0);

    // ---- layer 2: GAT(64 -> 4x32 concat): packed fp16 logits+accum; x2h fp16 (OUTH) ----
    k_alds1<<<NB32, 256, 0, stream>>>(x1h, U1p, aldsEh);
    k_gatx<64, 64><<<NB4, 256, 0, stream>>>(rp, srcs2, aldsEh, x1h, msg1h);
    k_mfma<64, 32, 0, 1><<<dim3(NTW, 4), 256, 0, stream>>>(msg1h, 256, 64, wg1rpk, 4096,
                                                           (float*)x2h, 128, 32, bg1, 32);

    // ---- layer 3: RGCN(128->32)+relu; L3 MFMA split 6-tiles x 3 y-slices ----
    k_mfmaL3<<<dim3(NTW, 3), 256, 0, stream>>>(x2h, Wcatpk, x3, ybuf3h);
    k_agg2<<<NB4, 256, 0, stream>>>(rp, srcs2, ybuf3h, brg2, U2p, x3, x3h, aldsEh);

    // ---- layer 4: GAT(32 -> 4x16, mean heads) + relu + tanh ----
    k_gatx<32, 32><<<NB4, 256, 0, stream>>>(rp, srcs2, aldsEh, x3h, msg2h);
    k_final<<<NB32, 256, 0, stream>>>(msg2h, Wstk, bg2, out);
}